// Round 1
// baseline (2948.210 us; speedup 1.0000x reference)
//
#include <hip/hip_runtime.h>
#include <hip/hip_bf16.h>
#include <math.h>

#define A_DIM 8
#define B_DIM 2048
#define C_DIM 512
#define M_TOT (A_DIM*B_DIM)   // 16384
#define HID_DIM (4*C_DIM)     // 2048
#define NBLK 4

typedef __attribute__((ext_vector_type(8))) short bf16x8;
typedef __attribute__((ext_vector_type(4))) float f32x4;
typedef __attribute__((ext_vector_type(8))) unsigned short ushort8v;
typedef __attribute__((ext_vector_type(4))) unsigned short ushort4v;

__device__ __forceinline__ unsigned short f2bf(float f) {
  union { float f; unsigned int u; } x; x.f = f;
  unsigned int r = x.u + 0x7fffu + ((x.u >> 16) & 1u);
  return (unsigned short)(r >> 16);
}
__device__ __forceinline__ float bf2f(unsigned short b) {
  union { unsigned int u; float f; } x; x.u = ((unsigned int)b) << 16;
  return x.f;
}

// ---------------------------------------------------------------- GEMM
// C[m][n] = sum_k A[m][k] * B[n][k]   (both bf16-split, row stride Kp)
// 128x128 tile, 4 waves (2x2 of 64x64), 16x16x32 bf16 MFMA, BK=32,
// global_load_lds width-16 staging (m97 structure).
#define BM 128
#define BN 128
#define BK 32

enum { EPI_F32 = 0, EPI_POSBIAS = 1, EPI_SPLIT = 2, EPI_GELU_SPLIT = 3, EPI_BIAS = 4 };

template<int EPI>
__global__ __launch_bounds__(256)
void gemm_bt(const unsigned short* __restrict__ Aa,
             const unsigned short* __restrict__ Bw,
             int Kp, int N,
             float* __restrict__ outF,
             const float* __restrict__ bias,
             unsigned short* __restrict__ outS)
{
  __shared__ unsigned short As[BM*BK];
  __shared__ unsigned short Bs[BN*BK];
  const int tid  = threadIdx.x;
  const int wid  = tid >> 6;
  const int lane = tid & 63;
  const int m0 = blockIdx.y * BM;
  const int n0 = blockIdx.x * BN;
  const int wr = wid >> 1, wc = wid & 1;

  f32x4 acc[4][4];
#pragma unroll
  for (int i = 0; i < 4; ++i)
#pragma unroll
    for (int j = 0; j < 4; ++j) acc[i][j] = (f32x4){0.f, 0.f, 0.f, 0.f};

  // staging: chunk e = wid*128 + call*64 + lane covers 16B; row=e>>2, kc=e&3
  const int e0 = wid * 128 + lane;
  const int r0 = e0 >> 2, kc0 = e0 & 3;
  const int e1 = e0 + 64;
  const int r1 = e1 >> 2, kc1 = e1 & 3;

  const unsigned short* gA0 = Aa + (size_t)(m0 + r0) * Kp + kc0 * 8;
  const unsigned short* gA1 = Aa + (size_t)(m0 + r1) * Kp + kc1 * 8;
  const unsigned short* gB0 = Bw + (size_t)(n0 + r0) * Kp + kc0 * 8;
  const unsigned short* gB1 = Bw + (size_t)(n0 + r1) * Kp + kc1 * 8;

  unsigned short* ldsA = As + wid * 1024;  // wave-uniform base (elems)
  unsigned short* ldsB = Bs + wid * 1024;

  const int fr = lane & 15;
  const int kb = lane >> 4;

  for (int k0 = 0; k0 < Kp; k0 += BK) {
    __builtin_amdgcn_global_load_lds((const __attribute__((address_space(1))) void*)(gA0 + k0),
                                     (__attribute__((address_space(3))) void*)(ldsA), 16, 0, 0);
    __builtin_amdgcn_global_load_lds((const __attribute__((address_space(1))) void*)(gA1 + k0),
                                     (__attribute__((address_space(3))) void*)(ldsA + 512), 16, 0, 0);
    __builtin_amdgcn_global_load_lds((const __attribute__((address_space(1))) void*)(gB0 + k0),
                                     (__attribute__((address_space(3))) void*)(ldsB), 16, 0, 0);
    __builtin_amdgcn_global_load_lds((const __attribute__((address_space(1))) void*)(gB1 + k0),
                                     (__attribute__((address_space(3))) void*)(ldsB + 512), 16, 0, 0);
    __syncthreads();

    bf16x8 af[4], bf[4];
#pragma unroll
    for (int i = 0; i < 4; ++i)
      af[i] = *(const bf16x8*)&As[(wr * 64 + i * 16 + fr) * BK + kb * 8];
#pragma unroll
    for (int j = 0; j < 4; ++j)
      bf[j] = *(const bf16x8*)&Bs[(wc * 64 + j * 16 + fr) * BK + kb * 8];
#pragma unroll
    for (int i = 0; i < 4; ++i)
#pragma unroll
      for (int j = 0; j < 4; ++j)
        acc[i][j] = __builtin_amdgcn_mfma_f32_16x16x32_bf16(af[i], bf[j], acc[i][j], 0, 0, 0);
    __syncthreads();
  }

  // epilogue: C/D layout col=lane&15, row=(lane>>4)*4+reg (m89-verified)
  const int rq = lane >> 4;
#pragma unroll
  for (int i = 0; i < 4; ++i) {
#pragma unroll
    for (int j = 0; j < 4; ++j) {
      const int col = n0 + wc * 64 + j * 16 + fr;
#pragma unroll
      for (int r = 0; r < 4; ++r) {
        const int row = m0 + wr * 64 + i * 16 + rq * 4 + r;
        float v = acc[i][j][r];
        if constexpr (EPI == EPI_F32) {
          outF[(size_t)row * N + col] = v;
        } else if constexpr (EPI == EPI_POSBIAS) {
          outF[(size_t)row * N + col] = v + bias[(size_t)(row & (B_DIM - 1)) * N + col];
        } else if constexpr (EPI == EPI_BIAS) {
          outF[(size_t)row * N + col] = v + bias[col];
        } else if constexpr (EPI == EPI_SPLIT) {
          unsigned short hi = f2bf(v);
          unsigned short lo = f2bf(v - bf2f(hi));
          size_t base = (size_t)row * 3 * N;
          outS[base + col] = hi;
          outS[base + N + col] = lo;
          outS[base + 2 * N + col] = hi;
        } else {  // EPI_GELU_SPLIT
          float t = v + bias[col];
          float g = 0.5f * t * (1.0f + erff(t * 0.70710678118654752f));
          unsigned short hi = f2bf(g);
          unsigned short lo = f2bf(g - bf2f(hi));
          size_t base = (size_t)row * 3 * N;
          outS[base + col] = hi;
          outS[base + N + col] = lo;
          outS[base + 2 * N + col] = hi;
        }
      }
    }
  }
}

// ------------------------------------------------- LN (+residual) -> bf16 split
template<bool ADDRES>
__global__ __launch_bounds__(64)
void ln_split_kernel(const float* __restrict__ S,
                     const float* __restrict__ g, const float* __restrict__ b,
                     unsigned short* __restrict__ outS)
{
  const int row = blockIdx.x;
  const int t = threadIdx.x;
  const float* p = S + (size_t)row * C_DIM + t * 8;
  float4 v0 = *(const float4*)p;
  float4 v1 = *(const float4*)(p + 4);
  float x[8] = {v0.x, v0.y, v0.z, v0.w, v1.x, v1.y, v1.z, v1.w};
  float sum = 0.f;
#pragma unroll
  for (int k = 0; k < 8; ++k) sum += x[k];
#pragma unroll
  for (int off = 32; off; off >>= 1) sum += __shfl_xor(sum, off, 64);
  const float mean = sum * (1.0f / C_DIM);
  float sq = 0.f;
#pragma unroll
  for (int k = 0; k < 8; ++k) { float d = x[k] - mean; sq += d * d; }
#pragma unroll
  for (int off = 32; off; off >>= 1) sq += __shfl_xor(sq, off, 64);
  const float inv = 1.0f / sqrtf(sq * (1.0f / C_DIM) + 1e-5f);

  ushort8v hi8, lo8;
#pragma unroll
  for (int k = 0; k < 8; ++k) {
    const int col = t * 8 + k;
    float val = (x[k] - mean) * inv * g[col] + b[col];
    if (ADDRES) val += x[k];
    unsigned short h = f2bf(val);
    hi8[k] = h;
    lo8[k] = f2bf(val - bf2f(h));
  }
  size_t base = (size_t)row * 3 * C_DIM + t * 8;
  *(ushort8v*)&outS[base] = hi8;
  *(ushort8v*)&outS[base + C_DIM] = lo8;
  *(ushort8v*)&outS[base + 2 * C_DIM] = hi8;
}

// ------------------------------------------------- fp32 -> bf16x3 split
// ACT: [hi | lo | hi]; weights: [hi | hi | lo]
template<bool ACT>
__global__ __launch_bounds__(128)
void split3_kernel(const float* __restrict__ in, unsigned short* __restrict__ out, int K)
{
  const int r = blockIdx.y;
  const int c4 = (blockIdx.x * 128 + threadIdx.x) * 4;
  if (c4 >= K) return;
  float4 v = *(const float4*)&in[(size_t)r * K + c4];
  float vv[4] = {v.x, v.y, v.z, v.w};
  ushort4v hi, lo;
#pragma unroll
  for (int k = 0; k < 4; ++k) {
    unsigned short h = f2bf(vv[k]);
    hi[k] = h;
    lo[k] = f2bf(vv[k] - bf2f(h));
  }
  size_t base = (size_t)r * 3 * K + c4;
  *(ushort4v*)&out[base] = hi;
  if (ACT) {
    *(ushort4v*)&out[base + K] = lo;
    *(ushort4v*)&out[base + 2 * K] = hi;
  } else {
    *(ushort4v*)&out[base + K] = hi;
    *(ushort4v*)&out[base + 2 * K] = lo;
  }
}

// ------------------------------------------------- positional bias (f64 fidelity)
__global__ __launch_bounds__(256)
void posbias_kernel(float* __restrict__ pb)
{
  const int idx = blockIdx.x * 256 + threadIdx.x;  // 2048*256
  const int j = idx >> 8;
  const int p = idx & 255;
  double ang = (double)j * exp(-(double)p * (log(10000.0) / 128.0));
  pb[(size_t)j * C_DIM + 2 * p]     = (float)sin(ang);
  pb[(size_t)j * C_DIM + 2 * p + 1] = (float)cos(ang);
}

// ------------------------------------------------- 3-pass scan: s += cumsum_b(u)
__global__ __launch_bounds__(256)
void scan_partial(const float* __restrict__ u, float* __restrict__ part)
{
  const int idx = blockIdx.x * 256 + threadIdx.x;  // 256*512
  const int g = idx >> 9, c = idx & 511;
  const float* p = u + (size_t)g * 64 * 512 + c;
  float s = 0.f;
#pragma unroll
  for (int i = 0; i < 64; ++i) s += p[i * 512];
  part[(size_t)g * 512 + c] = s;
}

__global__ __launch_bounds__(256)
void scan_ex(float* __restrict__ part)
{
  const int idx = blockIdx.x * 256 + threadIdx.x;  // 8*512
  const int a = idx >> 9, c = idx & 511;
  float run = 0.f;
  for (int ch = 0; ch < 32; ++ch) {
    const size_t o = (size_t)(a * 32 + ch) * 512 + c;
    float v = part[o];
    part[o] = run;
    run += v;
  }
}

__global__ __launch_bounds__(256)
void scan_apply(const float* __restrict__ u, const float* __restrict__ part,
                float* __restrict__ s)
{
  const int idx = blockIdx.x * 256 + threadIdx.x;  // 256*512
  const int g = idx >> 9, c = idx & 511;
  float run = part[(size_t)g * 512 + c];
  const float* pu = u + (size_t)g * 64 * 512 + c;
  float* ps = s + (size_t)g * 64 * 512 + c;
#pragma unroll
  for (int i = 0; i < 64; ++i) {
    run += pu[i * 512];
    ps[i * 512] += run;
  }
}

// ================================================================ launcher
extern "C" void kernel_launch(void* const* d_in, const int* in_sizes, int n_in,
                              void* d_out, int out_size, void* d_ws, size_t ws_size,
                              hipStream_t stream)
{
  const float* x      = (const float*)d_in[0];
  const float* weight = (const float*)d_in[1];
  // d_in[2] = Wq, d_in[3] = Wk : dead code (softmax over size-1 axis == 1.0)
  const float* Wv     = (const float*)d_in[4];
  const float* Wo     = (const float*)d_in[5];
  const float* ln1g   = (const float*)d_in[6];
  const float* ln1b   = (const float*)d_in[7];
  const float* ln2g   = (const float*)d_in[8];
  const float* ln2b   = (const float*)d_in[9];
  const float* fc1w   = (const float*)d_in[10];
  const float* fc1b   = (const float*)d_in[11];
  const float* fc2w   = (const float*)d_in[12];
  const float* fc2b   = (const float*)d_in[13];
  float* s = (float*)d_out;

  char* ws = (char*)d_ws;
  float* pb            = (float*)(ws + (size_t)(0) );          // 4 MB
  float* u             = (float*)(ws + ((size_t)4  << 20));    // 32 MB
  float* part          = (float*)(ws + ((size_t)36 << 20));    // 0.5 MB
  unsigned short* actA = (unsigned short*)(ws + ((size_t)40  << 20));  // 48 MB
  unsigned short* actB = (unsigned short*)(ws + ((size_t)88  << 20));  // 48 MB
  unsigned short* hid  = (unsigned short*)(ws + ((size_t)136 << 20));  // 96 MB
  unsigned short* w_s  = (unsigned short*)(ws + ((size_t)232 << 20));  // 1.5 MB
  unsigned short* wv_s = (unsigned short*)(ws + ((size_t)234 << 20));  // 1.5 MB
  unsigned short* wo_s = (unsigned short*)(ws + ((size_t)236 << 20));  // 1.5 MB
  unsigned short* fc1s = (unsigned short*)(ws + ((size_t)238 << 20));  // 6 MB
  unsigned short* fc2s = (unsigned short*)(ws + ((size_t)244 << 20));  // 6 MB

  posbias_kernel<<<2048, 256, 0, stream>>>(pb);
  split3_kernel<false><<<dim3(1, 512), 128, 0, stream>>>(weight, w_s, 512);
  split3_kernel<false><<<dim3(1, 2048), 128, 0, stream>>>(fc1w, fc1s, 512);
  split3_kernel<false><<<dim3(4, 512), 128, 0, stream>>>(fc2w, fc2s, 2048);
  split3_kernel<true><<<dim3(1, 16384), 128, 0, stream>>>(x, actA, 512);

  // s = x @ weight^T + posbias
  gemm_bt<EPI_POSBIAS><<<dim3(4, 128), 256, 0, stream>>>(actA, w_s, 1536, 512, s, pb, nullptr);

  for (int blk = 0; blk < NBLK; ++blk) {
    split3_kernel<false><<<dim3(1, 512), 128, 0, stream>>>(Wv + (size_t)blk * 512 * 512, wv_s, 512);
    split3_kernel<false><<<dim3(1, 512), 128, 0, stream>>>(Wo + (size_t)blk * 512 * 512, wo_s, 512);

    // h = LN1(s) -> split
    ln_split_kernel<false><<<16384, 64, 0, stream>>>(s, ln1g, ln1b, actA);
    // v = h @ Wv^T -> split
    gemm_bt<EPI_SPLIT><<<dim3(4, 128), 256, 0, stream>>>(actA, wv_s, 1536, 512, nullptr, nullptr, actB);
    // u = v @ Wo^T  (cumsum commutes with the matmul)
    gemm_bt<EPI_F32><<<dim3(4, 128), 256, 0, stream>>>(actB, wo_s, 1536, 512, u, nullptr, nullptr);
    // s += cumsum_b(u)
    scan_partial<<<512, 256, 0, stream>>>(u, part);
    scan_ex<<<16, 256, 0, stream>>>(part);
    scan_apply<<<512, 256, 0, stream>>>(u, part, s);
    // s2 = LN2(s) + s -> split
    ln_split_kernel<true><<<16384, 64, 0, stream>>>(s, ln2g, ln2b, actA);
    // FFN in two M=8192 halves to bound hid-split workspace
    for (int h = 0; h < 2; ++h) {
      const unsigned short* aPtr = actA + (size_t)h * 8192 * 1536;
      gemm_bt<EPI_GELU_SPLIT><<<dim3(16, 64), 256, 0, stream>>>(aPtr, fc1s, 1536, 2048,
                                                                nullptr, fc1b, hid);
      gemm_bt<EPI_BIAS><<<dim3(4, 64), 256, 0, stream>>>(hid, fc2s, 6144, 512,
                                                         s + (size_t)h * 8192 * 512, fc2b, nullptr);
    }
  }
  (void)in_sizes; (void)n_in; (void)out_size; (void)ws_size;
}

// Round 4
// 2418.536 us; speedup vs baseline: 1.2190x; 1.2190x over previous
//
#include <hip/hip_runtime.h>
#include <hip/hip_bf16.h>
#include <math.h>

#define A_DIM 8
#define B_DIM 2048
#define C_DIM 512
#define NBLK 4

typedef __attribute__((ext_vector_type(8))) short bf16x8;
typedef __attribute__((ext_vector_type(4))) float f32x4;
typedef __attribute__((ext_vector_type(8))) unsigned short ushort8v;
typedef __attribute__((ext_vector_type(4))) unsigned short ushort4v;

__device__ __forceinline__ unsigned short f2bf(float f) {
  union { float f; unsigned int u; } x; x.f = f;
  unsigned int r = x.u + 0x7fffu + ((x.u >> 16) & 1u);
  return (unsigned short)(r >> 16);
}
__device__ __forceinline__ float bf2f(unsigned short b) {
  union { unsigned int u; float f; } x; x.u = ((unsigned int)b) << 16;
  return x.f;
}

// ---------------------------------------------------------------- GEMM
// C[m][n] = sum_k A[m][k]*B[n][k].  A stored [hi|lo] (stride KpA), logical
// segment 3 wraps to hi (kA = k0-Kwrap for k0>=Kwrap).  B stored [hi|hi|lo]
// (stride KpB).  128x128 tile, 4 waves 2x2, BK=32, 16x16x32 bf16 MFMA,
// global_load_lds(16B) with both-sides XOR swizzle (chunk ^= (row>>1)&3):
// each 16-lane b128 read phase covers all 8 bank-groups (2-way = free).
// Split-K via blockIdx.z (kLen per z); EPI_ATOMIC accumulates via atomicAdd.
// bBlkStride: B base += (m0>>9)*bBlkStride (batched per-512-row B matrices).
#define BM 128
#define BN 128
#define BK 32

enum { EPI_F32 = 0, EPI_POSBIAS = 1, EPI_GELU_SPLIT = 3, EPI_ATOMIC = 4 };

template<int EPI>
__global__ __launch_bounds__(256)
void gemm_bt(const unsigned short* __restrict__ Aa,
             const unsigned short* __restrict__ Bw,
             int KpA, int KpB, int Kwrap, int kLen, int N, long bBlkStride,
             float* __restrict__ outF,
             const float* __restrict__ bias,
             unsigned short* __restrict__ outS)
{
  __shared__ unsigned short smem[8192];  // A slots [0,512), B slots [512,1024)
  const int tid  = threadIdx.x;
  const int wid  = tid >> 6;
  const int lane = tid & 63;
  const int m0 = blockIdx.y * BM;
  const int n0 = blockIdx.x * BN;
  const int wr = wid >> 1, wc = wid & 1;
  const int kBeg = blockIdx.z * kLen;
  Bw += (size_t)(m0 >> 9) * bBlkStride;

  f32x4 acc[4][4];
#pragma unroll
  for (int i = 0; i < 4; ++i)
#pragma unroll
    for (int j = 0; j < 4; ++j) acc[i][j] = (f32x4){0.f, 0.f, 0.f, 0.f};

  // LDS slot t holds global chunk g=(t&3)^((r>>1)&3) of row r=t>>2 (rule #21)
  const unsigned short* gp[4];
#pragma unroll
  for (int c = 0; c < 4; ++c) {
    const int t = c * 256 + tid;
    if (c < 2) {
      const int r = t >> 2;
      const int g = (t & 3) ^ ((r >> 1) & 3);
      gp[c] = Aa + (size_t)(m0 + r) * KpA + g * 8;
    } else {
      const int tb = t - 512;
      const int r = tb >> 2;
      const int g = (tb & 3) ^ ((r >> 1) & 3);
      gp[c] = Bw + (size_t)(n0 + r) * KpB + g * 8;
    }
  }

  const int fr = lane & 15;
  const int kb = lane >> 4;

  for (int k0 = kBeg; k0 < kBeg + kLen; k0 += BK) {
    const int kA = k0 - (k0 >= Kwrap ? Kwrap : 0);
#pragma unroll
    for (int c = 0; c < 4; ++c) {
      const int koff = (c < 2) ? kA : k0;
      __builtin_amdgcn_global_load_lds(
          (const __attribute__((address_space(1))) void*)(gp[c] + koff),
          (__attribute__((address_space(3))) void*)(smem + (c * 256 + wid * 64) * 8),
          16, 0, 0);
    }
    __syncthreads();

    bf16x8 af[4], bg[4];
#pragma unroll
    for (int i = 0; i < 4; ++i) {
      const int r = wr * 64 + i * 16 + fr;
      const int slot = r * 4 + (kb ^ ((r >> 1) & 3));
      af[i] = *(const bf16x8*)&smem[slot * 8];
    }
#pragma unroll
    for (int j = 0; j < 4; ++j) {
      const int r = wc * 64 + j * 16 + fr;
      const int slot = r * 4 + (kb ^ ((r >> 1) & 3));
      bg[j] = *(const bf16x8*)&smem[4096 + slot * 8];
    }
#pragma unroll
    for (int i = 0; i < 4; ++i)
#pragma unroll
      for (int j = 0; j < 4; ++j)
        acc[i][j] = __builtin_amdgcn_mfma_f32_16x16x32_bf16(af[i], bg[j], acc[i][j], 0, 0, 0);
    __syncthreads();
  }

  // epilogue: C/D layout col=lane&15, row=(lane>>4)*4+reg (m89-verified)
  const int rq = lane >> 4;
#pragma unroll
  for (int i = 0; i < 4; ++i) {
#pragma unroll
    for (int j = 0; j < 4; ++j) {
      const int col = n0 + wc * 64 + j * 16 + fr;
#pragma unroll
      for (int r = 0; r < 4; ++r) {
        const int row = m0 + wr * 64 + i * 16 + rq * 4 + r;
        float v = acc[i][j][r];
        if constexpr (EPI == EPI_F32) {
          outF[(size_t)row * N + col] = v;
        } else if constexpr (EPI == EPI_POSBIAS) {
          outF[(size_t)row * N + col] = v + bias[(size_t)(row & (B_DIM - 1)) * N + col];
        } else if constexpr (EPI == EPI_ATOMIC) {
          atomicAdd(&outF[(size_t)row * N + col], v);
        } else {  // EPI_GELU_SPLIT
          float t = v + bias[col];
          float g = 0.5f * t * (1.0f + erff(t * 0.70710678118654752f));
          unsigned short hi = f2bf(g);
          unsigned short lo = f2bf(g - bf2f(hi));
          size_t base = (size_t)row * 2 * N;
          outS[base + col] = hi;
          outS[base + N + col] = lo;
        }
      }
    }
  }
}

// ------------------------------------------------- LN (+residual) -> bf16 [hi|lo]
template<bool ADDRES>
__global__ __launch_bounds__(64)
void ln_split_kernel(const float* __restrict__ S,
                     const float* __restrict__ g, const float* __restrict__ b,
                     unsigned short* __restrict__ outS)
{
  const int row = blockIdx.x;
  const int t = threadIdx.x;
  const float* p = S + (size_t)row * C_DIM + t * 8;
  float4 v0 = *(const float4*)p;
  float4 v1 = *(const float4*)(p + 4);
  float x[8] = {v0.x, v0.y, v0.z, v0.w, v1.x, v1.y, v1.z, v1.w};
  float sum = 0.f;
#pragma unroll
  for (int k = 0; k < 8; ++k) sum += x[k];
#pragma unroll
  for (int off = 32; off; off >>= 1) sum += __shfl_xor(sum, off, 64);
  const float mean = sum * (1.0f / C_DIM);
  float sq = 0.f;
#pragma unroll
  for (int k = 0; k < 8; ++k) { float d = x[k] - mean; sq += d * d; }
#pragma unroll
  for (int off = 32; off; off >>= 1) sq += __shfl_xor(sq, off, 64);
  const float inv = 1.0f / sqrtf(sq * (1.0f / C_DIM) + 1e-5f);

  ushort8v hi8, lo8;
#pragma unroll
  for (int k = 0; k < 8; ++k) {
    const int col = t * 8 + k;
    float val = (x[k] - mean) * inv * g[col] + b[col];
    if (ADDRES) val += x[k];
    unsigned short h = f2bf(val);
    hi8[k] = h;
    lo8[k] = f2bf(val - bf2f(h));
  }
  size_t base = (size_t)row * 2 * C_DIM + t * 8;
  *(ushort8v*)&outS[base] = hi8;
  *(ushort8v*)&outS[base + C_DIM] = lo8;
}

// ------------------------------------------------- fp32 -> bf16 split
// ACT: [hi|lo] (stride 2K); weights: [hi|hi|lo] (stride 3K)
template<bool ACT>
__global__ __launch_bounds__(128)
void split3_kernel(const float* __restrict__ in, unsigned short* __restrict__ out, int K)
{
  const int r = blockIdx.y;
  const int c4 = (blockIdx.x * 128 + threadIdx.x) * 4;
  if (c4 >= K) return;
  float4 v = *(const float4*)&in[(size_t)r * K + c4];
  float vv[4] = {v.x, v.y, v.z, v.w};
  ushort4v hi, lo;
#pragma unroll
  for (int k = 0; k < 4; ++k) {
    unsigned short h = f2bf(vv[k]);
    hi[k] = h;
    lo[k] = f2bf(vv[k] - bf2f(h));
  }
  if (ACT) {
    size_t base = (size_t)r * 2 * K + c4;
    *(ushort4v*)&out[base] = hi;
    *(ushort4v*)&out[base + K] = lo;
  } else {
    size_t base = (size_t)r * 3 * K + c4;
    *(ushort4v*)&out[base] = hi;
    *(ushort4v*)&out[base + K] = hi;
    *(ushort4v*)&out[base + 2 * K] = lo;
  }
}

// ------------------------------------------------- 512x512 transpose (x4 blocks)
__global__ __launch_bounds__(256)
void transpose512(const float* __restrict__ in, float* __restrict__ out)
{
  __shared__ float t[32][33];
  const size_t ao = (size_t)blockIdx.z * 512 * 512;
  const int bx = blockIdx.x * 32, by = blockIdx.y * 32;
  const int tx = threadIdx.x & 31, ty4 = (threadIdx.x >> 5) * 4;
#pragma unroll
  for (int k = 0; k < 4; ++k)
    t[ty4 + k][tx] = in[ao + (size_t)(by + ty4 + k) * 512 + bx + tx];
  __syncthreads();
#pragma unroll
  for (int k = 0; k < 4; ++k)
    out[ao + (size_t)(bx + ty4 + k) * 512 + by + tx] = t[tx][ty4 + k];
}

// ------------------------------------------------- positional bias (f64 fidelity)
__global__ __launch_bounds__(256)
void posbias_kernel(float* __restrict__ pb)
{
  const int idx = blockIdx.x * 256 + threadIdx.x;  // 2048*256
  const int j = idx >> 8;
  const int p = idx & 255;
  double ang = (double)j * exp(-(double)p * (log(10000.0) / 128.0));
  pb[(size_t)j * C_DIM + 2 * p]     = (float)sin(ang);
  pb[(size_t)j * C_DIM + 2 * p + 1] = (float)cos(ang);
}

// ------------------------------------------------- fills
__global__ __launch_bounds__(256)
void bias_fill_kernel(float* __restrict__ s, const float* __restrict__ b)
{
  const int idx = blockIdx.x * 256 + threadIdx.x;   // 8192*256
  const int row = idx >> 7;
  const int c4 = (idx & 127) * 4;
  float4 v = *(const float4*)&b[c4];
  *(float4*)&s[(size_t)row * C_DIM + c4] = v;
}

__global__ __launch_bounds__(256)
void zero_kernel(float* __restrict__ p)
{
  const size_t i = ((size_t)blockIdx.x * 256 + threadIdx.x) * 4;
  *(float4*)&p[i] = (float4){0.f, 0.f, 0.f, 0.f};
}

// ------------------------------------------------- 3-pass scan: s += cumsum_b(u)
__global__ __launch_bounds__(256)
void scan_partial(const float* __restrict__ u, float* __restrict__ part)
{
  const int idx = blockIdx.x * 256 + threadIdx.x;  // 256*512
  const int g = idx >> 9, c = idx & 511;
  const float* p = u + (size_t)g * 64 * 512 + c;
  float s = 0.f;
#pragma unroll
  for (int i = 0; i < 64; ++i) s += p[i * 512];
  part[(size_t)g * 512 + c] = s;
}

__global__ __launch_bounds__(256)
void scan_ex(float* __restrict__ part)
{
  const int idx = blockIdx.x * 256 + threadIdx.x;  // 8*512
  const int a = idx >> 9, c = idx & 511;
  float run = 0.f;
  for (int ch = 0; ch < 32; ++ch) {
    const size_t o = (size_t)(a * 32 + ch) * 512 + c;
    float v = part[o];
    part[o] = run;
    run += v;
  }
}

__global__ __launch_bounds__(256)
void scan_apply(const float* __restrict__ u, const float* __restrict__ part,
                float* __restrict__ s)
{
  const int idx = blockIdx.x * 256 + threadIdx.x;  // 256*512
  const int g = idx >> 9, c = idx & 511;
  float run = part[(size_t)g * 512 + c];
  const float* pu = u + (size_t)g * 64 * 512 + c;
  float* ps = s + (size_t)g * 64 * 512 + c;
#pragma unroll
  for (int i = 0; i < 64; ++i) {
    run += pu[i * 512];
    ps[i * 512] += run;
  }
}

// ================================================================ launcher
extern "C" void kernel_launch(void* const* d_in, const int* in_sizes, int n_in,
                              void* d_out, int out_size, void* d_ws, size_t ws_size,
                              hipStream_t stream)
{
  const float* x      = (const float*)d_in[0];
  const float* weight = (const float*)d_in[1];
  // d_in[2] = Wq, d_in[3] = Wk : dead (softmax over size-1 axis == 1.0)
  const float* Wv     = (const float*)d_in[4];
  const float* Wo     = (const float*)d_in[5];
  const float* ln1g   = (const float*)d_in[6];
  const float* ln1b   = (const float*)d_in[7];
  const float* ln2g   = (const float*)d_in[8];
  const float* ln2b   = (const float*)d_in[9];
  const float* fc1w   = (const float*)d_in[10];
  const float* fc1b   = (const float*)d_in[11];
  const float* fc2w   = (const float*)d_in[12];
  const float* fc2b   = (const float*)d_in[13];
  float* s = (float*)d_out;

  char* ws = (char*)d_ws;
  float* pb            = (float*)(ws);                                  // 4 MB
  float* u             = (float*)(ws + ((size_t)4   << 20));            // 32 MB
  float* part          = (float*)(ws + ((size_t)36  << 20));            // 0.5 MB
  unsigned short* actA = (unsigned short*)(ws + ((size_t)40  << 20));   // 32 MB
  float* wvT           = (float*)(ws + ((size_t)72  << 20));            // 4 MB
  float* wcombF        = (float*)(ws + ((size_t)76  << 20));            // 4 MB
  unsigned short* wo_s = (unsigned short*)(ws + ((size_t)80  << 20));   // 4 MB (act-split)
  unsigned short* wcomb_s = (unsigned short*)(ws + ((size_t)84 << 20)); // 6 MB
  unsigned short* wvT_s   = (unsigned short*)(ws + ((size_t)90 << 20)); // 6 MB
  unsigned short* hid  = (unsigned short*)(ws + ((size_t)104 << 20));   // 128 MB
  unsigned short* w_s  = (unsigned short*)(ws + ((size_t)232 << 20));   // 1.5 MB
  unsigned short* fc1s = (unsigned short*)(ws + ((size_t)238 << 20));   // 6 MB
  unsigned short* fc2s = (unsigned short*)(ws + ((size_t)244 << 20));   // 6 MB

  // ---- prep (loop-invariant) ----
  posbias_kernel<<<2048, 256, 0, stream>>>(pb);
  transpose512<<<dim3(16, 16, 4), 256, 0, stream>>>(Wv, wvT);
  split3_kernel<false><<<dim3(1, 512),   128, 0, stream>>>(weight, w_s, 512);
  split3_kernel<false><<<dim3(1, 2048),  128, 0, stream>>>(fc1w, fc1s, 512);
  split3_kernel<false><<<dim3(4, 512),   128, 0, stream>>>(fc2w, fc2s, 2048);
  split3_kernel<true ><<<dim3(1, 16384), 128, 0, stream>>>(x, actA, 512);
  split3_kernel<true ><<<dim3(1, 2048),  128, 0, stream>>>(Wo, wo_s, 512);
  split3_kernel<false><<<dim3(1, 2048),  128, 0, stream>>>(wvT, wvT_s, 512);
  // Wcomb[a] = Wo[a] @ Wv2d[a]  (one batched launch; B base steps per 512 rows)
  gemm_bt<EPI_F32><<<dim3(4, 16, 1), 256, 0, stream>>>(
      wo_s, wvT_s, 1024, 1536, 1024, 1536, 512, (long)512 * 1536, wcombF, nullptr, nullptr);
  split3_kernel<false><<<dim3(1, 2048), 128, 0, stream>>>(wcombF, wcomb_s, 512);

  // s = x @ weight^T + posbias
  gemm_bt<EPI_POSBIAS><<<dim3(4, 128, 1), 256, 0, stream>>>(
      actA, w_s, 1024, 1536, 1024, 1536, 512, 0, s, pb, nullptr);

  for (int blk = 0; blk < NBLK; ++blk) {
    // h = LN1(s) -> split
    ln_split_kernel<false><<<16384, 64, 0, stream>>>(s, ln1g, ln1b, actA);
    // u = h @ Wcomb[blk]^T   (cumsum commutes with the matmul), split-K=2
    zero_kernel<<<8192, 256, 0, stream>>>(u);
    gemm_bt<EPI_ATOMIC><<<dim3(4, 128, 2), 256, 0, stream>>>(
        actA, wcomb_s + (size_t)blk * 512 * 1536, 1024, 1536, 1024, 768, 512, 0,
        u, nullptr, nullptr);
    // s += cumsum_b(u)
    scan_partial<<<512, 256, 0, stream>>>(u, part);
    scan_ex<<<16, 256, 0, stream>>>(part);
    scan_apply<<<512, 256, 0, stream>>>(u, part, s);
    // s2 = LN2(s) + s -> split
    ln_split_kernel<true><<<16384, 64, 0, stream>>>(s, ln2g, ln2b, actA);
    // FFN over full M=16384
    gemm_bt<EPI_GELU_SPLIT><<<dim3(16, 128, 1), 256, 0, stream>>>(
        actA, fc1s, 1024, 1536, 1024, 1536, 2048, 0, nullptr, fc1b, hid);
    bias_fill_kernel<<<8192, 256, 0, stream>>>(s, fc2b);
    gemm_bt<EPI_ATOMIC><<<dim3(4, 128, 2), 256, 0, stream>>>(
        hid, fc2s, 4096, 6144, 4096, 3072, 512, 0, s, nullptr, nullptr);
  }
  (void)in_sizes; (void)n_in; (void)out_size; (void)ws_size;
}

// Round 7
// 2143.451 us; speedup vs baseline: 1.3755x; 1.1283x over previous
//
#include <hip/hip_runtime.h>
#include <hip/hip_bf16.h>
#include <math.h>

#define A_DIM 8
#define B_DIM 2048
#define C_DIM 512
#define NBLK 4

typedef __attribute__((ext_vector_type(8))) short bf16x8;
typedef __attribute__((ext_vector_type(4))) float f32x4;
typedef __attribute__((ext_vector_type(8))) unsigned short ushort8v;
typedef __attribute__((ext_vector_type(4))) unsigned short ushort4v;

__device__ __forceinline__ unsigned short f2bf(float f) {
  union { float f; unsigned int u; } x; x.f = f;
  unsigned int r = x.u + 0x7fffu + ((x.u >> 16) & 1u);
  return (unsigned short)(r >> 16);
}
__device__ __forceinline__ float bf2f(unsigned short b) {
  union { unsigned int u; float f; } x; x.u = ((unsigned int)b) << 16;
  return x.f;
}

// ---------------------------------------------------------------- GEMM
// C[m][n] = sum_k A[m][k]*B[n][k] over logical K' = 3K (bf16 hi/lo 3-term split:
// Ahi*Bhi + Alo*Bhi + Ahi*Blo).  Both operands stored [hi|lo] (stride Kp = 2K):
//   A: seg0 hi (direct), seg1 lo (direct), seg2 hi -> kA = k0 - 2K
//   B: seg0 hi (direct), seg1 hi -> k0-K,   seg2 lo -> k0-K
// i.e. kA = k0 - (k0>=wrapA ? wrapA : 0) with wrapA=2K; kB same with wrapB=K.
// 128x128 tile, 4 waves 2x2, BK=32, 16x16x32 bf16 MFMA, global_load_lds(16B)
// with both-sides XOR swizzle (chunk ^= (row>>1)&3): conflict-free ds_read_b128
// (verified round 4: SQ_LDS_BANK_CONFLICT = 0).
// XCD-chunked bijective block swizzle (T1/m204): contiguous row-major grid
// chunk per XCD -> A y-band + B panels L2-resident.
// Split-K via lz (kLen per z); EPI_ATOMIC accumulates via atomicAdd.
// bBlkStride: B base += (m0>>9)*bBlkStride (batched per-512-row B matrices).
#define BM 128
#define BN 128
#define BK 32

enum { EPI_F32 = 0, EPI_POSBIAS = 1, EPI_GELU_SPLIT = 3, EPI_ATOMIC = 4 };

template<int EPI>
__global__ __launch_bounds__(256)
void gemm_bt(const unsigned short* __restrict__ Aa,
             const unsigned short* __restrict__ Bw,
             int KpA, int KpB, int wrapA, int wrapB, int kLen, int N,
             long bBlkStride,
             float* __restrict__ outF,
             const float* __restrict__ bias,
             unsigned short* __restrict__ outS)
{
  __shared__ unsigned short smem[8192];  // A slots [0,512), B slots [512,1024)
  const int tid  = threadIdx.x;
  const int wid  = tid >> 6;
  const int lane = tid & 63;

  // ---- XCD-chunked bijective swizzle (m204): hw id -> logical (lx,ly,lz)
  const int gx = gridDim.x, gy = gridDim.y;
  const long nwg  = (long)gx * gy * gridDim.z;
  const long orig = blockIdx.x + (long)gx * blockIdx.y + (long)gx * gy * blockIdx.z;
  const int  xcd  = (int)(orig & 7);
  const long q = nwg >> 3, r = nwg & 7;
  const long base = (xcd < r) ? (long)xcd * (q + 1) : r * (q + 1) + (long)(xcd - r) * q;
  const long logical = base + (orig >> 3);
  const int lx = (int)(logical % gx);
  const long t2 = logical / gx;
  const int ly = (int)(t2 % gy);
  const int lz = (int)(t2 / gy);

  const int m0 = ly * BM;
  const int n0 = lx * BN;
  const int wr = wid >> 1, wc = wid & 1;
  const int kBeg = lz * kLen;
  Bw += (size_t)(m0 >> 9) * bBlkStride;

  f32x4 acc[4][4];
#pragma unroll
  for (int i = 0; i < 4; ++i)
#pragma unroll
    for (int j = 0; j < 4; ++j) acc[i][j] = (f32x4){0.f, 0.f, 0.f, 0.f};

  // LDS slot t holds global chunk g=(t&3)^((r>>1)&3) of row r=t>>2 (rule #21)
  const unsigned short* gp[4];
#pragma unroll
  for (int c = 0; c < 4; ++c) {
    const int t = c * 256 + tid;
    if (c < 2) {
      const int rr = t >> 2;
      const int g = (t & 3) ^ ((rr >> 1) & 3);
      gp[c] = Aa + (size_t)(m0 + rr) * KpA + g * 8;
    } else {
      const int tb = t - 512;
      const int rr = tb >> 2;
      const int g = (tb & 3) ^ ((rr >> 1) & 3);
      gp[c] = Bw + (size_t)(n0 + rr) * KpB + g * 8;
    }
  }

  const int fr = lane & 15;
  const int kb = lane >> 4;

  for (int k0 = kBeg; k0 < kBeg + kLen; k0 += BK) {
    const int kA = k0 - (k0 >= wrapA ? wrapA : 0);
    const int kB = k0 - (k0 >= wrapB ? wrapB : 0);
#pragma unroll
    for (int c = 0; c < 4; ++c) {
      const int koff = (c < 2) ? kA : kB;
      __builtin_amdgcn_global_load_lds(
          (const __attribute__((address_space(1))) void*)(gp[c] + koff),
          (__attribute__((address_space(3))) void*)(smem + (c * 256 + wid * 64) * 8),
          16, 0, 0);
    }
    __syncthreads();

    bf16x8 af[4], bg[4];
#pragma unroll
    for (int i = 0; i < 4; ++i) {
      const int rr = wr * 64 + i * 16 + fr;
      const int slot = rr * 4 + (kb ^ ((rr >> 1) & 3));
      af[i] = *(const bf16x8*)&smem[slot * 8];
    }
#pragma unroll
    for (int j = 0; j < 4; ++j) {
      const int rr = wc * 64 + j * 16 + fr;
      const int slot = rr * 4 + (kb ^ ((rr >> 1) & 3));
      bg[j] = *(const bf16x8*)&smem[4096 + slot * 8];
    }
#pragma unroll
    for (int i = 0; i < 4; ++i)
#pragma unroll
      for (int j = 0; j < 4; ++j)
        acc[i][j] = __builtin_amdgcn_mfma_f32_16x16x32_bf16(af[i], bg[j], acc[i][j], 0, 0, 0);
    __syncthreads();
  }

  // epilogue: C/D layout col=lane&15, row=(lane>>4)*4+reg (m89-verified)
  const int rq = lane >> 4;
#pragma unroll
  for (int i = 0; i < 4; ++i) {
#pragma unroll
    for (int j = 0; j < 4; ++j) {
      const int col = n0 + wc * 64 + j * 16 + fr;
#pragma unroll
      for (int rg = 0; rg < 4; ++rg) {
        const int row = m0 + wr * 64 + i * 16 + rq * 4 + rg;
        float v = acc[i][j][rg];
        if constexpr (EPI == EPI_F32) {
          outF[(size_t)row * N + col] = v;
        } else if constexpr (EPI == EPI_POSBIAS) {
          outF[(size_t)row * N + col] = v + bias[(size_t)(row & (B_DIM - 1)) * N + col];
        } else if constexpr (EPI == EPI_ATOMIC) {
          atomicAdd(&outF[(size_t)row * N + col], v);
        } else {  // EPI_GELU_SPLIT
          float t = v + bias[col];
          float g = 0.5f * t * (1.0f + erff(t * 0.70710678118654752f));
          unsigned short hi = f2bf(g);
          unsigned short lo = f2bf(g - bf2f(hi));
          size_t ob = (size_t)row * 2 * N;
          outS[ob + col] = hi;
          outS[ob + N + col] = lo;
        }
      }
    }
  }
}

// ------------------------------------------------- LN (+residual) -> bf16 [hi|lo]
template<bool ADDRES>
__global__ __launch_bounds__(64)
void ln_split_kernel(const float* __restrict__ S,
                     const float* __restrict__ g, const float* __restrict__ b,
                     unsigned short* __restrict__ outS)
{
  const int row = blockIdx.x;
  const int t = threadIdx.x;
  const float* p = S + (size_t)row * C_DIM + t * 8;
  float4 v0 = *(const float4*)p;
  float4 v1 = *(const float4*)(p + 4);
  float x[8] = {v0.x, v0.y, v0.z, v0.w, v1.x, v1.y, v1.z, v1.w};
  float sum = 0.f;
#pragma unroll
  for (int k = 0; k < 8; ++k) sum += x[k];
#pragma unroll
  for (int off = 32; off; off >>= 1) sum += __shfl_xor(sum, off, 64);
  const float mean = sum * (1.0f / C_DIM);
  float sq = 0.f;
#pragma unroll
  for (int k = 0; k < 8; ++k) { float d = x[k] - mean; sq += d * d; }
#pragma unroll
  for (int off = 32; off; off >>= 1) sq += __shfl_xor(sq, off, 64);
  const float inv = 1.0f / sqrtf(sq * (1.0f / C_DIM) + 1e-5f);

  ushort8v hi8, lo8;
#pragma unroll
  for (int k = 0; k < 8; ++k) {
    const int col = t * 8 + k;
    float val = (x[k] - mean) * inv * g[col] + b[col];
    if (ADDRES) val += x[k];
    unsigned short h = f2bf(val);
    hi8[k] = h;
    lo8[k] = f2bf(val - bf2f(h));
  }
  size_t base = (size_t)row * 2 * C_DIM + t * 8;
  *(ushort8v*)&outS[base] = hi8;
  *(ushort8v*)&outS[base + C_DIM] = lo8;
}

// ------------------------------------------------- fp32 -> bf16 [hi|lo] (stride 2K)
__global__ __launch_bounds__(128)
void split2_kernel(const float* __restrict__ in, unsigned short* __restrict__ out, int K)
{
  const int r = blockIdx.y;
  const int c4 = (blockIdx.x * 128 + threadIdx.x) * 4;
  if (c4 >= K) return;
  float4 v = *(const float4*)&in[(size_t)r * K + c4];
  float vv[4] = {v.x, v.y, v.z, v.w};
  ushort4v hi, lo;
#pragma unroll
  for (int k = 0; k < 4; ++k) {
    unsigned short h = f2bf(vv[k]);
    hi[k] = h;
    lo[k] = f2bf(vv[k] - bf2f(h));
  }
  size_t base = (size_t)r * 2 * K + c4;
  *(ushort4v*)&out[base] = hi;
  *(ushort4v*)&out[base + K] = lo;
}

// ------------------------------------------------- 512x512 transpose (x4 blocks)
__global__ __launch_bounds__(256)
void transpose512(const float* __restrict__ in, float* __restrict__ out)
{
  __shared__ float t[32][33];
  const size_t ao = (size_t)blockIdx.z * 512 * 512;
  const int bx = blockIdx.x * 32, by = blockIdx.y * 32;
  const int tx = threadIdx.x & 31, ty4 = (threadIdx.x >> 5) * 4;
#pragma unroll
  for (int k = 0; k < 4; ++k)
    t[ty4 + k][tx] = in[ao + (size_t)(by + ty4 + k) * 512 + bx + tx];
  __syncthreads();
#pragma unroll
  for (int k = 0; k < 4; ++k)
    out[ao + (size_t)(bx + ty4 + k) * 512 + by + tx] = t[tx][ty4 + k];
}

// ------------------------------------------------- positional bias (f64 fidelity)
__global__ __launch_bounds__(256)
void posbias_kernel(float* __restrict__ pb)
{
  const int idx = blockIdx.x * 256 + threadIdx.x;  // 2048*256
  const int j = idx >> 8;
  const int p = idx & 255;
  double ang = (double)j * exp(-(double)p * (log(10000.0) / 128.0));
  pb[(size_t)j * C_DIM + 2 * p]     = (float)sin(ang);
  pb[(size_t)j * C_DIM + 2 * p + 1] = (float)cos(ang);
}

// ------------------------------------------------- fills
__global__ __launch_bounds__(256)
void bias_fill_kernel(float* __restrict__ s, const float* __restrict__ b)
{
  const int idx = blockIdx.x * 256 + threadIdx.x;   // 8192*256
  const int row = idx >> 7;
  const int c4 = (idx & 127) * 4;
  float4 v = *(const float4*)&b[c4];
  *(float4*)&s[(size_t)row * C_DIM + c4] = v;
}

__global__ __launch_bounds__(256)
void zero_kernel(float* __restrict__ p)
{
  const size_t i = ((size_t)blockIdx.x * 256 + threadIdx.x) * 4;
  *(float4*)&p[i] = (float4){0.f, 0.f, 0.f, 0.f};
}

// ------------------------------------------------- 3-pass scan: s += cumsum_b(u)
__global__ __launch_bounds__(256)
void scan_partial(const float* __restrict__ u, float* __restrict__ part)
{
  const int idx = blockIdx.x * 256 + threadIdx.x;  // 256*512
  const int g = idx >> 9, c = idx & 511;
  const float* p = u + (size_t)g * 64 * 512 + c;
  float s = 0.f;
#pragma unroll
  for (int i = 0; i < 64; ++i) s += p[i * 512];
  part[(size_t)g * 512 + c] = s;
}

__global__ __launch_bounds__(256)
void scan_ex(float* __restrict__ part)
{
  const int idx = blockIdx.x * 256 + threadIdx.x;  // 8*512
  const int a = idx >> 9, c = idx & 511;
  float run = 0.f;
  for (int ch = 0; ch < 32; ++ch) {
    const size_t o = (size_t)(a * 32 + ch) * 512 + c;
    float v = part[o];
    part[o] = run;
    run += v;
  }
}

__global__ __launch_bounds__(256)
void scan_apply(const float* __restrict__ u, const float* __restrict__ part,
                float* __restrict__ s)
{
  const int idx = blockIdx.x * 256 + threadIdx.x;  // 256*512
  const int g = idx >> 9, c = idx & 511;
  float run = part[(size_t)g * 512 + c];
  const float* pu = u + (size_t)g * 64 * 512 + c;
  float* ps = s + (size_t)g * 64 * 512 + c;
#pragma unroll
  for (int i = 0; i < 64; ++i) {
    run += pu[i * 512];
    ps[i * 512] += run;
  }
}

// ================================================================ launcher
extern "C" void kernel_launch(void* const* d_in, const int* in_sizes, int n_in,
                              void* d_out, int out_size, void* d_ws, size_t ws_size,
                              hipStream_t stream)
{
  const float* x      = (const float*)d_in[0];
  const float* weight = (const float*)d_in[1];
  // d_in[2] = Wq, d_in[3] = Wk : dead (softmax over size-1 axis == 1.0)
  const float* Wv     = (const float*)d_in[4];
  const float* Wo     = (const float*)d_in[5];
  const float* ln1g   = (const float*)d_in[6];
  const float* ln1b   = (const float*)d_in[7];
  const float* ln2g   = (const float*)d_in[8];
  const float* ln2b   = (const float*)d_in[9];
  const float* fc1w   = (const float*)d_in[10];
  const float* fc1b   = (const float*)d_in[11];
  const float* fc2w   = (const float*)d_in[12];
  const float* fc2b   = (const float*)d_in[13];
  float* s = (float*)d_out;

  char* ws = (char*)d_ws;
  float* pb            = (float*)(ws);                                  // 4 MB
  float* u             = (float*)(ws + ((size_t)4   << 20));            // 32 MB
  float* part          = (float*)(ws + ((size_t)36  << 20));            // 0.5 MB
  unsigned short* actA = (unsigned short*)(ws + ((size_t)40  << 20));   // 32 MB
  float* wvT           = (float*)(ws + ((size_t)72  << 20));            // 4 MB
  float* wcombF        = (float*)(ws + ((size_t)76  << 20));            // 4 MB
  unsigned short* wo_s = (unsigned short*)(ws + ((size_t)80  << 20));   // 4 MB
  unsigned short* wcomb_s = (unsigned short*)(ws + ((size_t)84 << 20)); // 4 MB
  unsigned short* wvT_s   = (unsigned short*)(ws + ((size_t)90 << 20)); // 4 MB
  unsigned short* hid  = (unsigned short*)(ws + ((size_t)104 << 20));   // 128 MB
  unsigned short* w_s  = (unsigned short*)(ws + ((size_t)232 << 20));   // 2 MB
  unsigned short* fc1s = (unsigned short*)(ws + ((size_t)238 << 20));   // 4 MB
  unsigned short* fc2s = (unsigned short*)(ws + ((size_t)244 << 20));   // 4 MB

  // ---- prep (loop-invariant) ----
  posbias_kernel<<<2048, 256, 0, stream>>>(pb);
  transpose512<<<dim3(16, 16, 4), 256, 0, stream>>>(Wv, wvT);
  split2_kernel<<<dim3(1, 512),   128, 0, stream>>>(weight, w_s, 512);
  split2_kernel<<<dim3(1, 2048),  128, 0, stream>>>(fc1w, fc1s, 512);
  split2_kernel<<<dim3(4, 512),   128, 0, stream>>>(fc2w, fc2s, 2048);
  split2_kernel<<<dim3(1, 16384), 128, 0, stream>>>(x, actA, 512);
  split2_kernel<<<dim3(1, 2048),  128, 0, stream>>>(Wo, wo_s, 512);
  split2_kernel<<<dim3(1, 2048),  128, 0, stream>>>(wvT, wvT_s, 512);
  // Wcomb[a] = Wo[a] @ Wv2d[a]  (one batched launch; B base steps per 512 rows)
  gemm_bt<EPI_F32><<<dim3(4, 16, 1), 256, 0, stream>>>(
      wo_s, wvT_s, 1024, 1024, 1024, 512, 1536, 512, (long)512 * 1024,
      wcombF, nullptr, nullptr);
  split2_kernel<<<dim3(1, 2048), 128, 0, stream>>>(wcombF, wcomb_s, 512);

  // s = x @ weight^T + posbias
  gemm_bt<EPI_POSBIAS><<<dim3(4, 128, 1), 256, 0, stream>>>(
      actA, w_s, 1024, 1024, 1024, 512, 1536, 512, 0, s, pb, nullptr);

  for (int blk = 0; blk < NBLK; ++blk) {
    // h = LN1(s) -> split
    ln_split_kernel<false><<<16384, 64, 0, stream>>>(s, ln1g, ln1b, actA);
    // u = h @ Wcomb[blk]^T   (cumsum commutes with the matmul), split-K=2
    zero_kernel<<<8192, 256, 0, stream>>>(u);
    gemm_bt<EPI_ATOMIC><<<dim3(4, 128, 2), 256, 0, stream>>>(
        actA, wcomb_s + (size_t)blk * 512 * 1024, 1024, 1024, 1024, 512, 768, 512, 0,
        u, nullptr, nullptr);
    // s += cumsum_b(u)
    scan_partial<<<512, 256, 0, stream>>>(u, part);
    scan_ex<<<16, 256, 0, stream>>>(part);
    scan_apply<<<512, 256, 0, stream>>>(u, part, s);
    // s2 = LN2(s) + s -> split
    ln_split_kernel<true><<<16384, 64, 0, stream>>>(s, ln2g, ln2b, actA);
    // FFN over full M=16384
    gemm_bt<EPI_GELU_SPLIT><<<dim3(16, 128, 1), 256, 0, stream>>>(
        actA, fc1s, 1024, 1024, 1024, 512, 1536, 2048, 0, nullptr, fc1b, hid);
    bias_fill_kernel<<<8192, 256, 0, stream>>>(s, fc2b);
    gemm_bt<EPI_ATOMIC><<<dim3(4, 128, 2), 256, 0, stream>>>(
        hid, fc2s, 4096, 4096, 4096, 2048, 3072, 512, 0, s, nullptr, nullptr);
  }
  (void)in_sizes; (void)n_in; (void)out_size; (void)ws_size;
}

// Round 9
// 1928.598 us; speedup vs baseline: 1.5287x; 1.1114x over previous
//
#include <hip/hip_runtime.h>
#include <hip/hip_bf16.h>
#include <math.h>

#define A_DIM 8
#define B_DIM 2048
#define C_DIM 512
#define NBLK 4

typedef __attribute__((ext_vector_type(8))) short bf16x8;
typedef __attribute__((ext_vector_type(4))) float f32x4;
typedef __attribute__((ext_vector_type(8))) unsigned short ushort8v;
typedef __attribute__((ext_vector_type(4))) unsigned short ushort4v;

__device__ __forceinline__ unsigned short f2bf(float f) {
  union { float f; unsigned int u; } x; x.f = f;
  unsigned int r = x.u + 0x7fffu + ((x.u >> 16) & 1u);
  return (unsigned short)(r >> 16);
}
__device__ __forceinline__ float bf2f(unsigned short b) {
  union { unsigned int u; float f; } x; x.u = ((unsigned int)b) << 16;
  return x.f;
}

// ---------------------------------------------------------------- GEMM
// C[m][n] = sum_k A[m][k]*B[n][k] over logical K' = 3K (bf16 hi/lo 3-term split:
// Ahi*Bhi + Alo*Bhi + Ahi*Blo).  Both operands stored [hi|lo] (stride Kp = 2K):
//   kA = k0 - (k0>=wrapA ? wrapA : 0), wrapA=2K (A: hi,lo,hi)
//   kB = k0 - (k0>=wrapB ? wrapB : 0), wrapB=K  (B: hi,hi,lo)
// 128x128 tile, 4 waves 2x2, BK=64 (halves barrier drains vs round-7's BK=32
// which measured MfmaUtil 21% / VALUBusy 41% -> drain-bound at short K),
// 16x16x32 bf16 MFMA, global_load_lds(16B), both-sides XOR swizzle for
// 8-chunk rows: LDS slot (row, c) holds global chunk c^(row&7); read chunk
// (s*4+kb)^(row&7): each 16-lane b128 phase covers all 8 bank-groups twice
// = 2-way = free (BK=32 variant verified round 4: BANK_CONFLICT = 0).
// XCD-chunked bijective block swizzle (T1/m204) -> verified round 7:
// FETCH 488 -> 122 MB.  Split-K via lz; EPI_ATOMIC accumulates via atomicAdd.
// bBlkStride: B base += (m0>>9)*bBlkStride (batched per-512-row B matrices).
#define BM 128
#define BN 128
#define BKT 64

enum { EPI_F32 = 0, EPI_POSBIAS = 1, EPI_GELU_SPLIT = 3, EPI_ATOMIC = 4 };

template<int EPI>
__global__ __launch_bounds__(256)
void gemm_bt(const unsigned short* __restrict__ Aa,
             const unsigned short* __restrict__ Bw,
             int KpA, int KpB, int wrapA, int wrapB, int kLen, int N,
             long bBlkStride,
             float* __restrict__ outF,
             const float* __restrict__ bias,
             unsigned short* __restrict__ outS)
{
  __shared__ unsigned short smem[16384];  // A elems [0,8192), B [8192,16384)
  const int tid  = threadIdx.x;
  const int wid  = tid >> 6;
  const int lane = tid & 63;

  // ---- XCD-chunked bijective swizzle (m204): hw id -> logical (lx,ly,lz)
  const int gx = gridDim.x, gy = gridDim.y;
  const long nwg  = (long)gx * gy * gridDim.z;
  const long orig = blockIdx.x + (long)gx * blockIdx.y + (long)gx * gy * blockIdx.z;
  const int  xcd  = (int)(orig & 7);
  const long q = nwg >> 3, r = nwg & 7;
  const long base = (xcd < r) ? (long)xcd * (q + 1) : r * (q + 1) + (long)(xcd - r) * q;
  const long logical = base + (orig >> 3);
  const int lx = (int)(logical % gx);
  const long t2 = logical / gx;
  const int ly = (int)(t2 % gy);
  const int lz = (int)(t2 / gy);

  const int m0 = ly * BM;
  const int n0 = lx * BN;
  const int wr = wid >> 1, wc = wid & 1;
  const int kBeg = lz * kLen;
  Bw += (size_t)(m0 >> 9) * bBlkStride;

  f32x4 acc[4][4];
#pragma unroll
  for (int i = 0; i < 4; ++i)
#pragma unroll
    for (int j = 0; j < 4; ++j) acc[i][j] = (f32x4){0.f, 0.f, 0.f, 0.f};

  // staging: 8 chunks/thread; slot t holds global chunk (t&7)^((t>>3)&7) of
  // row t>>3 (pre-swizzled source, rule #21)
  const unsigned short* gp[8];
#pragma unroll
  for (int c = 0; c < 8; ++c) {
    const int t = c * 256 + tid;
    if (c < 4) {
      const int rr = t >> 3;
      const int g = (t & 7) ^ (rr & 7);
      gp[c] = Aa + (size_t)(m0 + rr) * KpA + g * 8;
    } else {
      const int tb = t - 1024;
      const int rr = tb >> 3;
      const int g = (tb & 7) ^ (rr & 7);
      gp[c] = Bw + (size_t)(n0 + rr) * KpB + g * 8;
    }
  }

  const int fr = lane & 15;
  const int kb = lane >> 4;

  for (int k0 = kBeg; k0 < kBeg + kLen; k0 += BKT) {
    const int kA = k0 - (k0 >= wrapA ? wrapA : 0);
    const int kB = k0 - (k0 >= wrapB ? wrapB : 0);
#pragma unroll
    for (int c = 0; c < 8; ++c) {
      const int koff = (c < 4) ? kA : kB;
      __builtin_amdgcn_global_load_lds(
          (const __attribute__((address_space(1))) void*)(gp[c] + koff),
          (__attribute__((address_space(3))) void*)(smem + (c * 256 + wid * 64) * 8),
          16, 0, 0);
    }
    __syncthreads();

#pragma unroll
    for (int s = 0; s < 2; ++s) {
      bf16x8 af[4], bg[4];
#pragma unroll
      for (int i = 0; i < 4; ++i) {
        const int rr = wr * 64 + i * 16 + fr;
        const int ch = (s * 4 + kb) ^ (rr & 7);
        af[i] = *(const bf16x8*)&smem[rr * 64 + ch * 8];
      }
#pragma unroll
      for (int j = 0; j < 4; ++j) {
        const int rr = wc * 64 + j * 16 + fr;
        const int ch = (s * 4 + kb) ^ (rr & 7);
        bg[j] = *(const bf16x8*)&smem[8192 + rr * 64 + ch * 8];
      }
#pragma unroll
      for (int i = 0; i < 4; ++i)
#pragma unroll
        for (int j = 0; j < 4; ++j)
          acc[i][j] = __builtin_amdgcn_mfma_f32_16x16x32_bf16(af[i], bg[j], acc[i][j], 0, 0, 0);
    }
    __syncthreads();
  }

  // epilogue: C/D layout col=lane&15, row=(lane>>4)*4+reg (m89-verified)
  const int rq = lane >> 4;
#pragma unroll
  for (int i = 0; i < 4; ++i) {
#pragma unroll
    for (int j = 0; j < 4; ++j) {
      const int col = n0 + wc * 64 + j * 16 + fr;
#pragma unroll
      for (int rg = 0; rg < 4; ++rg) {
        const int row = m0 + wr * 64 + i * 16 + rq * 4 + rg;
        float v = acc[i][j][rg];
        if constexpr (EPI == EPI_F32) {
          outF[(size_t)row * N + col] = v;
        } else if constexpr (EPI == EPI_POSBIAS) {
          outF[(size_t)row * N + col] = v + bias[(size_t)(row & (B_DIM - 1)) * N + col];
        } else if constexpr (EPI == EPI_ATOMIC) {
          atomicAdd(&outF[(size_t)row * N + col], v);
        } else {  // EPI_GELU_SPLIT
          float t = v + bias[col];
          float g = 0.5f * t * (1.0f + erff(t * 0.70710678118654752f));
          unsigned short hi = f2bf(g);
          unsigned short lo = f2bf(g - bf2f(hi));
          size_t ob = (size_t)row * 2 * N;
          outS[ob + col] = hi;
          outS[ob + N + col] = lo;
        }
      }
    }
  }
}

// ------------------------------------------------- LN (+residual) -> bf16 [hi|lo]
template<bool ADDRES>
__global__ __launch_bounds__(64)
void ln_split_kernel(const float* __restrict__ S,
                     const float* __restrict__ g, const float* __restrict__ b,
                     unsigned short* __restrict__ outS)
{
  const int row = blockIdx.x;
  const int t = threadIdx.x;
  const float* p = S + (size_t)row * C_DIM + t * 8;
  float4 v0 = *(const float4*)p;
  float4 v1 = *(const float4*)(p + 4);
  float x[8] = {v0.x, v0.y, v0.z, v0.w, v1.x, v1.y, v1.z, v1.w};
  float sum = 0.f;
#pragma unroll
  for (int k = 0; k < 8; ++k) sum += x[k];
#pragma unroll
  for (int off = 32; off; off >>= 1) sum += __shfl_xor(sum, off, 64);
  const float mean = sum * (1.0f / C_DIM);
  float sq = 0.f;
#pragma unroll
  for (int k = 0; k < 8; ++k) { float d = x[k] - mean; sq += d * d; }
#pragma unroll
  for (int off = 32; off; off >>= 1) sq += __shfl_xor(sq, off, 64);
  const float inv = 1.0f / sqrtf(sq * (1.0f / C_DIM) + 1e-5f);

  ushort8v hi8, lo8;
#pragma unroll
  for (int k = 0; k < 8; ++k) {
    const int col = t * 8 + k;
    float val = (x[k] - mean) * inv * g[col] + b[col];
    if (ADDRES) val += x[k];
    unsigned short h = f2bf(val);
    hi8[k] = h;
    lo8[k] = f2bf(val - bf2f(h));
  }
  size_t base = (size_t)row * 2 * C_DIM + t * 8;
  *(ushort8v*)&outS[base] = hi8;
  *(ushort8v*)&outS[base + C_DIM] = lo8;
}

// ------------------------------------------------- fp32 -> bf16 [hi|lo] (stride 2K)
__global__ __launch_bounds__(128)
void split2_kernel(const float* __restrict__ in, unsigned short* __restrict__ out, int K)
{
  const int r = blockIdx.y;
  const int c4 = (blockIdx.x * 128 + threadIdx.x) * 4;
  if (c4 >= K) return;
  float4 v = *(const float4*)&in[(size_t)r * K + c4];
  float vv[4] = {v.x, v.y, v.z, v.w};
  ushort4v hi, lo;
#pragma unroll
  for (int k = 0; k < 4; ++k) {
    unsigned short h = f2bf(vv[k]);
    hi[k] = h;
    lo[k] = f2bf(vv[k] - bf2f(h));
  }
  size_t base = (size_t)r * 2 * K + c4;
  *(ushort4v*)&out[base] = hi;
  *(ushort4v*)&out[base + K] = lo;
}

// ------------------------------------------------- 512x512 transpose (x4 blocks)
__global__ __launch_bounds__(256)
void transpose512(const float* __restrict__ in, float* __restrict__ out)
{
  __shared__ float t[32][33];
  const size_t ao = (size_t)blockIdx.z * 512 * 512;
  const int bx = blockIdx.x * 32, by = blockIdx.y * 32;
  const int tx = threadIdx.x & 31, ty4 = (threadIdx.x >> 5) * 4;
#pragma unroll
  for (int k = 0; k < 4; ++k)
    t[ty4 + k][tx] = in[ao + (size_t)(by + ty4 + k) * 512 + bx + tx];
  __syncthreads();
#pragma unroll
  for (int k = 0; k < 4; ++k)
    out[ao + (size_t)(bx + ty4 + k) * 512 + by + tx] = t[tx][ty4 + k];
}

// ------------------------------------------------- positional bias (f64 fidelity)
__global__ __launch_bounds__(256)
void posbias_kernel(float* __restrict__ pb)
{
  const int idx = blockIdx.x * 256 + threadIdx.x;  // 2048*256
  const int j = idx >> 8;
  const int p = idx & 255;
  double ang = (double)j * exp(-(double)p * (log(10000.0) / 128.0));
  pb[(size_t)j * C_DIM + 2 * p]     = (float)sin(ang);
  pb[(size_t)j * C_DIM + 2 * p + 1] = (float)cos(ang);
}

// ------------------------------------------------- fills
__global__ __launch_bounds__(256)
void bias_fill_kernel(float* __restrict__ s, const float* __restrict__ b)
{
  const int idx = blockIdx.x * 256 + threadIdx.x;   // 8192*256
  const int row = idx >> 7;
  const int c4 = (idx & 127) * 4;
  float4 v = *(const float4*)&b[c4];
  *(float4*)&s[(size_t)row * C_DIM + c4] = v;
}

__global__ __launch_bounds__(256)
void zero_kernel(float* __restrict__ p)
{
  const size_t i = ((size_t)blockIdx.x * 256 + threadIdx.x) * 4;
  *(float4*)&p[i] = (float4){0.f, 0.f, 0.f, 0.f};
}

// ------------------------------------------------- 3-pass scan: s += cumsum_b(u)
__global__ __launch_bounds__(256)
void scan_partial(const float* __restrict__ u, float* __restrict__ part)
{
  const int idx = blockIdx.x * 256 + threadIdx.x;  // 256*512
  const int g = idx >> 9, c = idx & 511;
  const float* p = u + (size_t)g * 64 * 512 + c;
  float s = 0.f;
#pragma unroll
  for (int i = 0; i < 64; ++i) s += p[i * 512];
  part[(size_t)g * 512 + c] = s;
}

__global__ __launch_bounds__(256)
void scan_ex(float* __restrict__ part)
{
  const int idx = blockIdx.x * 256 + threadIdx.x;  // 8*512
  const int a = idx >> 9, c = idx & 511;
  float run = 0.f;
  for (int ch = 0; ch < 32; ++ch) {
    const size_t o = (size_t)(a * 32 + ch) * 512 + c;
    float v = part[o];
    part[o] = run;
    run += v;
  }
}

__global__ __launch_bounds__(256)
void scan_apply(const float* __restrict__ u, const float* __restrict__ part,
                float* __restrict__ s)
{
  const int idx = blockIdx.x * 256 + threadIdx.x;  // 256*512
  const int g = idx >> 9, c = idx & 511;
  float run = part[(size_t)g * 512 + c];
  const float* pu = u + (size_t)g * 64 * 512 + c;
  float* ps = s + (size_t)g * 64 * 512 + c;
#pragma unroll
  for (int i = 0; i < 64; ++i) {
    run += pu[i * 512];
    ps[i * 512] += run;
  }
}

// ================================================================ launcher
extern "C" void kernel_launch(void* const* d_in, const int* in_sizes, int n_in,
                              void* d_out, int out_size, void* d_ws, size_t ws_size,
                              hipStream_t stream)
{
  const float* x      = (const float*)d_in[0];
  const float* weight = (const float*)d_in[1];
  // d_in[2] = Wq, d_in[3] = Wk : dead (softmax over size-1 axis == 1.0)
  const float* Wv     = (const float*)d_in[4];
  const float* Wo     = (const float*)d_in[5];
  const float* ln1g   = (const float*)d_in[6];
  const float* ln1b   = (const float*)d_in[7];
  const float* ln2g   = (const float*)d_in[8];
  const float* ln2b   = (const float*)d_in[9];
  const float* fc1w   = (const float*)d_in[10];
  const float* fc1b   = (const float*)d_in[11];
  const float* fc2w   = (const float*)d_in[12];
  const float* fc2b   = (const float*)d_in[13];
  float* s = (float*)d_out;

  char* ws = (char*)d_ws;
  float* pb            = (float*)(ws);                                  // 4 MB
  float* u             = (float*)(ws + ((size_t)4   << 20));            // 32 MB
  float* part          = (float*)(ws + ((size_t)36  << 20));            // 0.5 MB
  unsigned short* actA = (unsigned short*)(ws + ((size_t)40  << 20));   // 32 MB
  float* wvT           = (float*)(ws + ((size_t)72  << 20));            // 4 MB
  float* wcombF        = (float*)(ws + ((size_t)76  << 20));            // 4 MB
  unsigned short* wo_s = (unsigned short*)(ws + ((size_t)80  << 20));   // 4 MB
  unsigned short* wcomb_s = (unsigned short*)(ws + ((size_t)84 << 20)); // 4 MB
  unsigned short* wvT_s   = (unsigned short*)(ws + ((size_t)90 << 20)); // 4 MB
  unsigned short* hid  = (unsigned short*)(ws + ((size_t)104 << 20));   // 128 MB
  unsigned short* w_s  = (unsigned short*)(ws + ((size_t)232 << 20));   // 2 MB
  unsigned short* fc1s = (unsigned short*)(ws + ((size_t)238 << 20));   // 4 MB
  unsigned short* fc2s = (unsigned short*)(ws + ((size_t)244 << 20));   // 4 MB

  // ---- prep (loop-invariant) ----
  posbias_kernel<<<2048, 256, 0, stream>>>(pb);
  transpose512<<<dim3(16, 16, 4), 256, 0, stream>>>(Wv, wvT);
  split2_kernel<<<dim3(1, 512),   128, 0, stream>>>(weight, w_s, 512);
  split2_kernel<<<dim3(1, 2048),  128, 0, stream>>>(fc1w, fc1s, 512);
  split2_kernel<<<dim3(4, 512),   128, 0, stream>>>(fc2w, fc2s, 2048);
  split2_kernel<<<dim3(1, 16384), 128, 0, stream>>>(x, actA, 512);
  split2_kernel<<<dim3(1, 2048),  128, 0, stream>>>(Wo, wo_s, 512);
  split2_kernel<<<dim3(1, 2048),  128, 0, stream>>>(wvT, wvT_s, 512);
  // Wcomb[a] = Wo[a] @ Wv2d[a]  (one batched launch; B base steps per 512 rows)
  gemm_bt<EPI_F32><<<dim3(4, 16, 1), 256, 0, stream>>>(
      wo_s, wvT_s, 1024, 1024, 1024, 512, 1536, 512, (long)512 * 1024,
      wcombF, nullptr, nullptr);
  split2_kernel<<<dim3(1, 2048), 128, 0, stream>>>(wcombF, wcomb_s, 512);

  // s = x @ weight^T + posbias
  gemm_bt<EPI_POSBIAS><<<dim3(4, 128, 1), 256, 0, stream>>>(
      actA, w_s, 1024, 1024, 1024, 512, 1536, 512, 0, s, pb, nullptr);

  for (int blk = 0; blk < NBLK; ++blk) {
    // h = LN1(s) -> split
    ln_split_kernel<false><<<16384, 64, 0, stream>>>(s, ln1g, ln1b, actA);
    // u = h @ Wcomb[blk]^T   (cumsum commutes with the matmul), split-K=2
    zero_kernel<<<8192, 256, 0, stream>>>(u);
    gemm_bt<EPI_ATOMIC><<<dim3(4, 128, 2), 256, 0, stream>>>(
        actA, wcomb_s + (size_t)blk * 512 * 1024, 1024, 1024, 1024, 512, 768, 512, 0,
        u, nullptr, nullptr);
    // s += cumsum_b(u)
    scan_partial<<<512, 256, 0, stream>>>(u, part);
    scan_ex<<<16, 256, 0, stream>>>(part);
    scan_apply<<<512, 256, 0, stream>>>(u, part, s);
    // s2 = LN2(s) + s -> split
    ln_split_kernel<true><<<16384, 64, 0, stream>>>(s, ln2g, ln2b, actA);
    // FFN over full M=16384
    gemm_bt<EPI_GELU_SPLIT><<<dim3(16, 128, 1), 256, 0, stream>>>(
        actA, fc1s, 1024, 1024, 1024, 512, 1536, 2048, 0, nullptr, fc1b, hid);
    bias_fill_kernel<<<8192, 256, 0, stream>>>(s, fc2b);
    gemm_bt<EPI_ATOMIC><<<dim3(4, 128, 2), 256, 0, stream>>>(
        hid, fc2s, 4096, 4096, 4096, 2048, 3072, 512, 0, s, nullptr, nullptr);
  }
  (void)in_sizes; (void)n_in; (void)out_size; (void)ws_size;
}

// Round 10
// 1433.594 us; speedup vs baseline: 2.0565x; 1.3453x over previous
//
#include <hip/hip_runtime.h>
#include <hip/hip_bf16.h>
#include <math.h>

#define A_DIM 8
#define B_DIM 2048
#define C_DIM 512
#define NBLK 4

typedef __attribute__((ext_vector_type(8))) short bf16x8;
typedef __attribute__((ext_vector_type(4))) float f32x4;
typedef __attribute__((ext_vector_type(8))) unsigned short ushort8v;
typedef __attribute__((ext_vector_type(4))) unsigned short ushort4v;

__device__ __forceinline__ unsigned short f2bf(float f) {
  union { float f; unsigned int u; } x; x.f = f;
  unsigned int r = x.u + 0x7fffu + ((x.u >> 16) & 1u);
  return (unsigned short)(r >> 16);
}
__device__ __forceinline__ float bf2f(unsigned short b) {
  union { unsigned int u; float f; } x; x.u = ((unsigned int)b) << 16;
  return x.f;
}

// ---------------------------------------------------------------- GEMM
// C[m][n] = sum_k A[m][k]*B[n][k] over logical K' = 3K (bf16 hi/lo 3-term split:
// Ahi*Bhi + Alo*Bhi + Ahi*Blo).  Both operands stored [hi|lo] (stride Kp = 2K):
//   kA = k0 - (k0>=wrapA ? wrapA : 0), wrapA=2K (A: hi,lo,hi)
//   kB = k0 - (k0>=wrapB ? wrapB : 0), wrapB=K  (B: hi,hi,lo)
// 128x128 tile, 4 waves 2x2, BK=64, 16x16x32 bf16 MFMA, global_load_lds(16B).
// DOUBLE-BUFFERED single-barrier pipeline (T3 minimal recipe): per K-step,
// { barrier (drains prev stage via compiler vmcnt(0)) ; issue stage(next) ;
//   ds_read cur ; MFMA } -- loads for t+1 fly during MFMA of t.  Round 7/9
// measured the 2-barrier variant drain-bound (MfmaUtil 21-24%, HBM 13%).
// Both-sides XOR swizzle for 8-chunk rows: LDS slot (row,c) holds global chunk
// c^(row&7); read chunk (s*4+kb)^(row&7) -> conflict-free (round 4/9: 0).
// XCD-chunked bijective block swizzle (m204) -> round 7: FETCH 488->122 MB.
// bBlkStride: B base += (m0>>9)*bBlkStride (batched per-512-row B matrices).
#define BM 128
#define BN 128
#define BKT 64

enum { EPI_F32 = 0, EPI_POSBIAS = 1, EPI_GELU_SPLIT = 3, EPI_BIASCOL = 5 };

template<int EPI>
__global__ __launch_bounds__(256)
void gemm_bt(const unsigned short* __restrict__ Aa,
             const unsigned short* __restrict__ Bw,
             int KpA, int KpB, int wrapA, int wrapB, int kLen, int N,
             long bBlkStride,
             float* __restrict__ outF,
             const float* __restrict__ bias,
             unsigned short* __restrict__ outS)
{
  __shared__ unsigned short smem[2][16384];  // per buf: A [0,8192), B [8192,16384)
  const int tid  = threadIdx.x;
  const int wid  = tid >> 6;
  const int lane = tid & 63;

  // ---- XCD-chunked bijective swizzle (m204): hw id -> logical (lx,ly,lz)
  const int gx = gridDim.x, gy = gridDim.y;
  const long nwg  = (long)gx * gy * gridDim.z;
  const long orig = blockIdx.x + (long)gx * blockIdx.y + (long)gx * gy * blockIdx.z;
  const int  xcd  = (int)(orig & 7);
  const long q = nwg >> 3, r = nwg & 7;
  const long base = (xcd < r) ? (long)xcd * (q + 1) : r * (q + 1) + (long)(xcd - r) * q;
  const long logical = base + (orig >> 3);
  const int lx = (int)(logical % gx);
  const long t2 = logical / gx;
  const int ly = (int)(t2 % gy);
  const int lz = (int)(t2 / gy);

  const int m0 = ly * BM;
  const int n0 = lx * BN;
  const int wr = wid >> 1, wc = wid & 1;
  const int kBeg = lz * kLen;
  Bw += (size_t)(m0 >> 9) * bBlkStride;

  f32x4 acc[4][4];
#pragma unroll
  for (int i = 0; i < 4; ++i)
#pragma unroll
    for (int j = 0; j < 4; ++j) acc[i][j] = (f32x4){0.f, 0.f, 0.f, 0.f};

  // staging: 8 chunks/thread; slot t holds global chunk (t&7)^((t>>3)&7) of
  // row t>>3 (pre-swizzled source, rule #21)
  const unsigned short* gp[8];
#pragma unroll
  for (int c = 0; c < 8; ++c) {
    const int t = c * 256 + tid;
    if (c < 4) {
      const int rr = t >> 3;
      const int g = (t & 7) ^ (rr & 7);
      gp[c] = Aa + (size_t)(m0 + rr) * KpA + g * 8;
    } else {
      const int tb = t - 1024;
      const int rr = tb >> 3;
      const int g = (tb & 7) ^ (rr & 7);
      gp[c] = Bw + (size_t)(n0 + rr) * KpB + g * 8;
    }
  }

  const int fr = lane & 15;
  const int kb = lane >> 4;
  const int kEnd = kBeg + kLen;

  auto stage = [&](int buf, int k0) {
    const int kA = k0 - (k0 >= wrapA ? wrapA : 0);
    const int kB = k0 - (k0 >= wrapB ? wrapB : 0);
#pragma unroll
    for (int c = 0; c < 8; ++c) {
      const int koff = (c < 4) ? kA : kB;
      __builtin_amdgcn_global_load_lds(
          (const __attribute__((address_space(1))) void*)(gp[c] + koff),
          (__attribute__((address_space(3))) void*)(&smem[buf][(c * 256 + wid * 64) * 8]),
          16, 0, 0);
    }
  };

  stage(0, kBeg);          // prologue: tile 0 -> buf 0
  int cur = 0;
  for (int k0 = kBeg; k0 < kEnd; k0 += BKT) {
    __syncthreads();       // drains prev stage (vmcnt) + fences prev reads
    if (k0 + BKT < kEnd) stage(cur ^ 1, k0 + BKT);   // overlap with MFMA below

#pragma unroll
    for (int s = 0; s < 2; ++s) {
      bf16x8 af[4], bg[4];
#pragma unroll
      for (int i = 0; i < 4; ++i) {
        const int rr = wr * 64 + i * 16 + fr;
        const int ch = (s * 4 + kb) ^ (rr & 7);
        af[i] = *(const bf16x8*)&smem[cur][rr * 64 + ch * 8];
      }
#pragma unroll
      for (int j = 0; j < 4; ++j) {
        const int rr = wc * 64 + j * 16 + fr;
        const int ch = (s * 4 + kb) ^ (rr & 7);
        bg[j] = *(const bf16x8*)&smem[cur][8192 + rr * 64 + ch * 8];
      }
#pragma unroll
      for (int i = 0; i < 4; ++i)
#pragma unroll
        for (int j = 0; j < 4; ++j)
          acc[i][j] = __builtin_amdgcn_mfma_f32_16x16x32_bf16(af[i], bg[j], acc[i][j], 0, 0, 0);
    }
    cur ^= 1;
  }

  // epilogue: C/D layout col=lane&15, row=(lane>>4)*4+reg (m89-verified)
  const int rq = lane >> 4;
#pragma unroll
  for (int i = 0; i < 4; ++i) {
#pragma unroll
    for (int j = 0; j < 4; ++j) {
      const int col = n0 + wc * 64 + j * 16 + fr;
#pragma unroll
      for (int rg = 0; rg < 4; ++rg) {
        const int row = m0 + wr * 64 + i * 16 + rq * 4 + rg;
        float v = acc[i][j][rg];
        if constexpr (EPI == EPI_F32) {
          outF[(size_t)row * N + col] = v;
        } else if constexpr (EPI == EPI_POSBIAS) {
          outF[(size_t)row * N + col] = v + bias[(size_t)(row & (B_DIM - 1)) * N + col];
        } else if constexpr (EPI == EPI_BIASCOL) {
          outF[(size_t)row * N + col] = v + bias[col];
        } else {  // EPI_GELU_SPLIT
          float t = v + bias[col];
          float g = 0.5f * t * (1.0f + erff(t * 0.70710678118654752f));
          unsigned short hi = f2bf(g);
          unsigned short lo = f2bf(g - bf2f(hi));
          size_t ob = (size_t)row * 2 * N;
          outS[ob + col] = hi;
          outS[ob + N + col] = lo;
        }
      }
    }
  }
}

// ------------------------------------------------- LN (+residual) -> bf16 [hi|lo]
template<bool ADDRES>
__global__ __launch_bounds__(64)
void ln_split_kernel(const float* __restrict__ S,
                     const float* __restrict__ g, const float* __restrict__ b,
                     unsigned short* __restrict__ outS)
{
  const int row = blockIdx.x;
  const int t = threadIdx.x;
  const float* p = S + (size_t)row * C_DIM + t * 8;
  float4 v0 = *(const float4*)p;
  float4 v1 = *(const float4*)(p + 4);
  float x[8] = {v0.x, v0.y, v0.z, v0.w, v1.x, v1.y, v1.z, v1.w};
  float sum = 0.f;
#pragma unroll
  for (int k = 0; k < 8; ++k) sum += x[k];
#pragma unroll
  for (int off = 32; off; off >>= 1) sum += __shfl_xor(sum, off, 64);
  const float mean = sum * (1.0f / C_DIM);
  float sq = 0.f;
#pragma unroll
  for (int k = 0; k < 8; ++k) { float d = x[k] - mean; sq += d * d; }
#pragma unroll
  for (int off = 32; off; off >>= 1) sq += __shfl_xor(sq, off, 64);
  const float inv = 1.0f / sqrtf(sq * (1.0f / C_DIM) + 1e-5f);

  ushort8v hi8, lo8;
#pragma unroll
  for (int k = 0; k < 8; ++k) {
    const int col = t * 8 + k;
    float val = (x[k] - mean) * inv * g[col] + b[col];
    if (ADDRES) val += x[k];
    unsigned short h = f2bf(val);
    hi8[k] = h;
    lo8[k] = f2bf(val - bf2f(h));
  }
  size_t base = (size_t)row * 2 * C_DIM + t * 8;
  *(ushort8v*)&outS[base] = hi8;
  *(ushort8v*)&outS[base + C_DIM] = lo8;
}

// ------------------------------------------------- fp32 -> bf16 [hi|lo] (stride 2K)
__global__ __launch_bounds__(128)
void split2_kernel(const float* __restrict__ in, unsigned short* __restrict__ out, int K)
{
  const int r = blockIdx.y;
  const int c4 = (blockIdx.x * 128 + threadIdx.x) * 4;
  if (c4 >= K) return;
  float4 v = *(const float4*)&in[(size_t)r * K + c4];
  float vv[4] = {v.x, v.y, v.z, v.w};
  ushort4v hi, lo;
#pragma unroll
  for (int k = 0; k < 4; ++k) {
    unsigned short h = f2bf(vv[k]);
    hi[k] = h;
    lo[k] = f2bf(vv[k] - bf2f(h));
  }
  size_t base = (size_t)r * 2 * K + c4;
  *(ushort4v*)&out[base] = hi;
  *(ushort4v*)&out[base + K] = lo;
}

// ------------------------------------------------- 512x512 transpose (x4 blocks)
__global__ __launch_bounds__(256)
void transpose512(const float* __restrict__ in, float* __restrict__ out)
{
  __shared__ float t[32][33];
  const size_t ao = (size_t)blockIdx.z * 512 * 512;
  const int bx = blockIdx.x * 32, by = blockIdx.y * 32;
  const int tx = threadIdx.x & 31, ty4 = (threadIdx.x >> 5) * 4;
#pragma unroll
  for (int k = 0; k < 4; ++k)
    t[ty4 + k][tx] = in[ao + (size_t)(by + ty4 + k) * 512 + bx + tx];
  __syncthreads();
#pragma unroll
  for (int k = 0; k < 4; ++k)
    out[ao + (size_t)(bx + ty4 + k) * 512 + by + tx] = t[tx][ty4 + k];
}

// ------------------------------------------------- positional bias (f64 fidelity)
__global__ __launch_bounds__(256)
void posbias_kernel(float* __restrict__ pb)
{
  const int idx = blockIdx.x * 256 + threadIdx.x;  // 2048*256
  const int j = idx >> 8;
  const int p = idx & 255;
  double ang = (double)j * exp(-(double)p * (log(10000.0) / 128.0));
  pb[(size_t)j * C_DIM + 2 * p]     = (float)sin(ang);
  pb[(size_t)j * C_DIM + 2 * p + 1] = (float)cos(ang);
}

// ------------------------------------------------- 2-pass scan: s += cumsum_b(u)
__global__ __launch_bounds__(256)
void scan_partial(const float* __restrict__ u, float* __restrict__ part)
{
  const int idx = blockIdx.x * 256 + threadIdx.x;  // 256*512
  const int g = idx >> 9, c = idx & 511;
  const float* p = u + (size_t)g * 64 * 512 + c;
  float s = 0.f;
#pragma unroll
  for (int i = 0; i < 64; ++i) s += p[i * 512];
  part[(size_t)g * 512 + c] = s;
}

// apply: block computes its own exclusive chunk-prefix (<=31 wave-uniform loads)
__global__ __launch_bounds__(256)
void scan_apply(const float* __restrict__ u, const float* __restrict__ part,
                float* __restrict__ s)
{
  const int idx = blockIdx.x * 256 + threadIdx.x;  // 256*512
  const int g = idx >> 9, c = idx & 511;
  const int a = g >> 5, ch = g & 31;
  float run = 0.f;
  for (int p = a * 32; p < a * 32 + ch; ++p)
    run += part[(size_t)p * 512 + c];
  const float* pu = u + (size_t)g * 64 * 512 + c;
  float* ps = s + (size_t)g * 64 * 512 + c;
#pragma unroll
  for (int i = 0; i < 64; ++i) {
    run += pu[i * 512];
    ps[i * 512] += run;
  }
}

// ================================================================ launcher
extern "C" void kernel_launch(void* const* d_in, const int* in_sizes, int n_in,
                              void* d_out, int out_size, void* d_ws, size_t ws_size,
                              hipStream_t stream)
{
  const float* x      = (const float*)d_in[0];
  const float* weight = (const float*)d_in[1];
  // d_in[2] = Wq, d_in[3] = Wk : dead (softmax over size-1 axis == 1.0)
  const float* Wv     = (const float*)d_in[4];
  const float* Wo     = (const float*)d_in[5];
  const float* ln1g   = (const float*)d_in[6];
  const float* ln1b   = (const float*)d_in[7];
  const float* ln2g   = (const float*)d_in[8];
  const float* ln2b   = (const float*)d_in[9];
  const float* fc1w   = (const float*)d_in[10];
  const float* fc1b   = (const float*)d_in[11];
  const float* fc2w   = (const float*)d_in[12];
  const float* fc2b   = (const float*)d_in[13];
  float* s = (float*)d_out;

  char* ws = (char*)d_ws;
  float* pb            = (float*)(ws);                                  // 4 MB
  float* u             = (float*)(ws + ((size_t)4   << 20));            // 32 MB
  float* part          = (float*)(ws + ((size_t)36  << 20));            // 0.5 MB
  unsigned short* actA = (unsigned short*)(ws + ((size_t)40  << 20));   // 32 MB
  float* wvT           = (float*)(ws + ((size_t)72  << 20));            // 4 MB
  float* wcombF        = (float*)(ws + ((size_t)76  << 20));            // 4 MB
  unsigned short* wo_s = (unsigned short*)(ws + ((size_t)80  << 20));   // 4 MB
  unsigned short* wcomb_s = (unsigned short*)(ws + ((size_t)84 << 20)); // 4 MB
  unsigned short* wvT_s   = (unsigned short*)(ws + ((size_t)90 << 20)); // 4 MB
  unsigned short* hid  = (unsigned short*)(ws + ((size_t)104 << 20));   // 128 MB
  unsigned short* w_s  = (unsigned short*)(ws + ((size_t)232 << 20));   // 2 MB
  unsigned short* fc1s = (unsigned short*)(ws + ((size_t)238 << 20));   // 4 MB
  unsigned short* fc2s = (unsigned short*)(ws + ((size_t)244 << 20));   // 4 MB

  // ---- prep (loop-invariant) ----
  posbias_kernel<<<2048, 256, 0, stream>>>(pb);
  transpose512<<<dim3(16, 16, 4), 256, 0, stream>>>(Wv, wvT);
  split2_kernel<<<dim3(1, 512),   128, 0, stream>>>(weight, w_s, 512);
  split2_kernel<<<dim3(1, 2048),  128, 0, stream>>>(fc1w, fc1s, 512);
  split2_kernel<<<dim3(4, 512),   128, 0, stream>>>(fc2w, fc2s, 2048);
  split2_kernel<<<dim3(1, 16384), 128, 0, stream>>>(x, actA, 512);
  split2_kernel<<<dim3(1, 2048),  128, 0, stream>>>(Wo, wo_s, 512);
  split2_kernel<<<dim3(1, 2048),  128, 0, stream>>>(wvT, wvT_s, 512);
  // Wcomb[a] = Wo[a] @ Wv2d[a]  (one batched launch; B base steps per 512 rows)
  gemm_bt<EPI_F32><<<dim3(4, 16, 1), 256, 0, stream>>>(
      wo_s, wvT_s, 1024, 1024, 1024, 512, 1536, 512, (long)512 * 1024,
      wcombF, nullptr, nullptr);
  split2_kernel<<<dim3(1, 2048), 128, 0, stream>>>(wcombF, wcomb_s, 512);

  // s = x @ weight^T + posbias
  gemm_bt<EPI_POSBIAS><<<dim3(4, 128, 1), 256, 0, stream>>>(
      actA, w_s, 1024, 1024, 1024, 512, 1536, 512, 0, s, pb, nullptr);

  for (int blk = 0; blk < NBLK; ++blk) {
    // h = LN1(s) -> split
    ln_split_kernel<false><<<16384, 64, 0, stream>>>(s, ln1g, ln1b, actA);
    // u = h @ Wcomb[blk]^T   (cumsum commutes with the matmul)
    gemm_bt<EPI_F32><<<dim3(4, 128, 1), 256, 0, stream>>>(
        actA, wcomb_s + (size_t)blk * 512 * 1024, 1024, 1024, 1024, 512, 1536, 512, 0,
        u, nullptr, nullptr);
    // s += cumsum_b(u)
    scan_partial<<<512, 256, 0, stream>>>(u, part);
    scan_apply<<<512, 256, 0, stream>>>(u, part, s);
    // s2 = LN2(s) + s -> split
    ln_split_kernel<true><<<16384, 64, 0, stream>>>(s, ln2g, ln2b, actA);
    // FFN over full M=16384
    gemm_bt<EPI_GELU_SPLIT><<<dim3(16, 128, 1), 256, 0, stream>>>(
        actA, fc1s, 1024, 1024, 1024, 512, 1536, 2048, 0, nullptr, fc1b, hid);
    gemm_bt<EPI_BIASCOL><<<dim3(4, 128, 1), 256, 0, stream>>>(
        hid, fc2s, 4096, 4096, 4096, 2048, 6144, 512, 0, s, fc2b, nullptr);
  }
  (void)in_sizes; (void)n_in; (void)out_size; (void)ws_size;
}

// Round 11
// 1354.667 us; speedup vs baseline: 2.1763x; 1.0583x over previous
//
#include <hip/hip_runtime.h>
#include <hip/hip_bf16.h>
#include <math.h>

#define A_DIM 8
#define B_DIM 2048
#define C_DIM 512
#define NBLK 4

typedef __attribute__((ext_vector_type(8))) short bf16x8;
typedef __attribute__((ext_vector_type(4))) float f32x4;
typedef __attribute__((ext_vector_type(8))) unsigned short ushort8v;
typedef __attribute__((ext_vector_type(4))) unsigned short ushort4v;

__device__ __forceinline__ unsigned short f2bf(float f) {
  union { float f; unsigned int u; } x; x.f = f;
  unsigned int r = x.u + 0x7fffu + ((x.u >> 16) & 1u);
  return (unsigned short)(r >> 16);
}
__device__ __forceinline__ float bf2f(unsigned short b) {
  union { unsigned int u; float f; } x; x.u = ((unsigned int)b) << 16;
  return x.f;
}

// Branchless exact-GELU via A&S 7.1.26 erfc (|erf err| <= 1.5e-7):
// library erff is branchy/divergent (~100 inst) and was ~40% of fc1 time
// (round 10: VALUBusy 49% vs MfmaUtil 29%).  This is ~15 VALU ops.
__device__ __forceinline__ float gelu_exact(float x) {
  float z = fabsf(x) * 0.70710678118654752f;
  float t = 1.0f / fmaf(0.3275911f, z, 1.0f);
  float p = t * fmaf(t, fmaf(t, fmaf(t, fmaf(t, 1.061405429f, -1.453152027f),
                                     1.421413741f), -0.284496736f), 0.254829592f);
  float erfc_z = p * __expf(-z * z);            // erfc(z), z >= 0
  float phi = (x >= 0.0f) ? fmaf(-0.5f, erfc_z, 1.0f) : 0.5f * erfc_z;
  return x * phi;
}

// ---------------------------------------------------------------- GEMM
// C[m][n] = sum_k A[m][k]*B[n][k] over logical K' = 3K (bf16 hi/lo 3-term split:
// Ahi*Bhi + Alo*Bhi + Ahi*Blo).  Both operands stored [hi|lo] (stride Kp = 2K):
//   kA = k0 - (k0>=wrapA ? wrapA : 0), wrapA=2K (A: hi,lo,hi)
//   kB = k0 - (k0>=wrapB ? wrapB : 0), wrapB=K  (B: hi,hi,lo)
// 128x128 tile, 4 waves 2x2, BK=64, 16x16x32 bf16 MFMA, global_load_lds(16B).
// DOUBLE-BUFFERED single-barrier pipeline (T3 minimal recipe): per K-step,
// { barrier (drains prev stage via compiler vmcnt(0)) ; issue stage(next) ;
//   ds_read cur ; MFMA } -- loads for t+1 fly during MFMA of t.
// Round 10: total 1929->1433, MfmaUtil 29%, conflicts 0.
// Both-sides XOR swizzle for 8-chunk rows: LDS slot (row,c) holds global chunk
// c^(row&7); read chunk (s*4+kb)^(row&7) -> conflict-free (round 4/9/10: 0).
// XCD-chunked bijective block swizzle (m204) -> round 7: FETCH 488->122 MB.
// bBlkStride: B base += (m0>>9)*bBlkStride (batched per-512-row B matrices).
#define BM 128
#define BN 128
#define BKT 64

enum { EPI_F32 = 0, EPI_POSBIAS = 1, EPI_GELU_SPLIT = 3, EPI_BIASCOL = 5 };

template<int EPI>
__global__ __launch_bounds__(256)
void gemm_bt(const unsigned short* __restrict__ Aa,
             const unsigned short* __restrict__ Bw,
             int KpA, int KpB, int wrapA, int wrapB, int kLen, int N,
             long bBlkStride,
             float* __restrict__ outF,
             const float* __restrict__ bias,
             unsigned short* __restrict__ outS)
{
  __shared__ unsigned short smem[2][16384];  // per buf: A [0,8192), B [8192,16384)
  const int tid  = threadIdx.x;
  const int wid  = tid >> 6;
  const int lane = tid & 63;

  // ---- XCD-chunked bijective swizzle (m204): hw id -> logical (lx,ly,lz)
  const int gx = gridDim.x, gy = gridDim.y;
  const long nwg  = (long)gx * gy * gridDim.z;
  const long orig = blockIdx.x + (long)gx * blockIdx.y + (long)gx * gy * blockIdx.z;
  const int  xcd  = (int)(orig & 7);
  const long q = nwg >> 3, r = nwg & 7;
  const long base = (xcd < r) ? (long)xcd * (q + 1) : r * (q + 1) + (long)(xcd - r) * q;
  const long logical = base + (orig >> 3);
  const int lx = (int)(logical % gx);
  const long t2 = logical / gx;
  const int ly = (int)(t2 % gy);
  const int lz = (int)(t2 / gy);

  const int m0 = ly * BM;
  const int n0 = lx * BN;
  const int wr = wid >> 1, wc = wid & 1;
  const int kBeg = lz * kLen;
  Bw += (size_t)(m0 >> 9) * bBlkStride;

  f32x4 acc[4][4];
#pragma unroll
  for (int i = 0; i < 4; ++i)
#pragma unroll
    for (int j = 0; j < 4; ++j) acc[i][j] = (f32x4){0.f, 0.f, 0.f, 0.f};

  // staging: 8 chunks/thread; slot t holds global chunk (t&7)^((t>>3)&7) of
  // row t>>3 (pre-swizzled source, rule #21)
  const unsigned short* gp[8];
#pragma unroll
  for (int c = 0; c < 8; ++c) {
    const int t = c * 256 + tid;
    if (c < 4) {
      const int rr = t >> 3;
      const int g = (t & 7) ^ (rr & 7);
      gp[c] = Aa + (size_t)(m0 + rr) * KpA + g * 8;
    } else {
      const int tb = t - 1024;
      const int rr = tb >> 3;
      const int g = (tb & 7) ^ (rr & 7);
      gp[c] = Bw + (size_t)(n0 + rr) * KpB + g * 8;
    }
  }

  const int fr = lane & 15;
  const int kb = lane >> 4;
  const int kEnd = kBeg + kLen;

  auto stage = [&](int buf, int k0) {
    const int kA = k0 - (k0 >= wrapA ? wrapA : 0);
    const int kB = k0 - (k0 >= wrapB ? wrapB : 0);
#pragma unroll
    for (int c = 0; c < 8; ++c) {
      const int koff = (c < 4) ? kA : kB;
      __builtin_amdgcn_global_load_lds(
          (const __attribute__((address_space(1))) void*)(gp[c] + koff),
          (__attribute__((address_space(3))) void*)(&smem[buf][(c * 256 + wid * 64) * 8]),
          16, 0, 0);
    }
  };

  stage(0, kBeg);          // prologue: tile 0 -> buf 0
  int cur = 0;
  for (int k0 = kBeg; k0 < kEnd; k0 += BKT) {
    __syncthreads();       // drains prev stage (vmcnt) + fences prev reads
    if (k0 + BKT < kEnd) stage(cur ^ 1, k0 + BKT);   // overlap with MFMA below

#pragma unroll
    for (int s = 0; s < 2; ++s) {
      bf16x8 af[4], bg[4];
#pragma unroll
      for (int i = 0; i < 4; ++i) {
        const int rr = wr * 64 + i * 16 + fr;
        const int ch = (s * 4 + kb) ^ (rr & 7);
        af[i] = *(const bf16x8*)&smem[cur][rr * 64 + ch * 8];
      }
#pragma unroll
      for (int j = 0; j < 4; ++j) {
        const int rr = wc * 64 + j * 16 + fr;
        const int ch = (s * 4 + kb) ^ (rr & 7);
        bg[j] = *(const bf16x8*)&smem[cur][8192 + rr * 64 + ch * 8];
      }
#pragma unroll
      for (int i = 0; i < 4; ++i)
#pragma unroll
        for (int j = 0; j < 4; ++j)
          acc[i][j] = __builtin_amdgcn_mfma_f32_16x16x32_bf16(af[i], bg[j], acc[i][j], 0, 0, 0);
    }
    cur ^= 1;
  }

  // epilogue: C/D layout col=lane&15, row=(lane>>4)*4+reg (m89-verified)
  const int rq = lane >> 4;
#pragma unroll
  for (int i = 0; i < 4; ++i) {
#pragma unroll
    for (int j = 0; j < 4; ++j) {
      const int col = n0 + wc * 64 + j * 16 + fr;
#pragma unroll
      for (int rg = 0; rg < 4; ++rg) {
        const int row = m0 + wr * 64 + i * 16 + rq * 4 + rg;
        float v = acc[i][j][rg];
        if constexpr (EPI == EPI_F32) {
          outF[(size_t)row * N + col] = v;
        } else if constexpr (EPI == EPI_POSBIAS) {
          outF[(size_t)row * N + col] = v + bias[(size_t)(row & (B_DIM - 1)) * N + col];
        } else if constexpr (EPI == EPI_BIASCOL) {
          outF[(size_t)row * N + col] = v + bias[col];
        } else {  // EPI_GELU_SPLIT
          float g = gelu_exact(v + bias[col]);
          unsigned short hi = f2bf(g);
          unsigned short lo = f2bf(g - bf2f(hi));
          size_t ob = (size_t)row * 2 * N;
          outS[ob + col] = hi;
          outS[ob + N + col] = lo;
        }
      }
    }
  }
}

// ------------------------------------------------- LN (+residual) -> bf16 [hi|lo]
template<bool ADDRES>
__global__ __launch_bounds__(64)
void ln_split_kernel(const float* __restrict__ S,
                     const float* __restrict__ g, const float* __restrict__ b,
                     unsigned short* __restrict__ outS)
{
  const int row = blockIdx.x;
  const int t = threadIdx.x;
  const float* p = S + (size_t)row * C_DIM + t * 8;
  float4 v0 = *(const float4*)p;
  float4 v1 = *(const float4*)(p + 4);
  float x[8] = {v0.x, v0.y, v0.z, v0.w, v1.x, v1.y, v1.z, v1.w};
  float sum = 0.f;
#pragma unroll
  for (int k = 0; k < 8; ++k) sum += x[k];
#pragma unroll
  for (int off = 32; off; off >>= 1) sum += __shfl_xor(sum, off, 64);
  const float mean = sum * (1.0f / C_DIM);
  float sq = 0.f;
#pragma unroll
  for (int k = 0; k < 8; ++k) { float d = x[k] - mean; sq += d * d; }
#pragma unroll
  for (int off = 32; off; off >>= 1) sq += __shfl_xor(sq, off, 64);
  const float inv = 1.0f / sqrtf(sq * (1.0f / C_DIM) + 1e-5f);

  ushort8v hi8, lo8;
#pragma unroll
  for (int k = 0; k < 8; ++k) {
    const int col = t * 8 + k;
    float val = (x[k] - mean) * inv * g[col] + b[col];
    if (ADDRES) val += x[k];
    unsigned short h = f2bf(val);
    hi8[k] = h;
    lo8[k] = f2bf(val - bf2f(h));
  }
  size_t base = (size_t)row * 2 * C_DIM + t * 8;
  *(ushort8v*)&outS[base] = hi8;
  *(ushort8v*)&outS[base + C_DIM] = lo8;
}

// ------------------------------------------------- fp32 -> bf16 [hi|lo] (stride 2K)
__global__ __launch_bounds__(128)
void split2_kernel(const float* __restrict__ in, unsigned short* __restrict__ out, int K)
{
  const int r = blockIdx.y;
  const int c4 = (blockIdx.x * 128 + threadIdx.x) * 4;
  if (c4 >= K) return;
  float4 v = *(const float4*)&in[(size_t)r * K + c4];
  float vv[4] = {v.x, v.y, v.z, v.w};
  ushort4v hi, lo;
#pragma unroll
  for (int k = 0; k < 4; ++k) {
    unsigned short h = f2bf(vv[k]);
    hi[k] = h;
    lo[k] = f2bf(vv[k] - bf2f(h));
  }
  size_t base = (size_t)r * 2 * K + c4;
  *(ushort4v*)&out[base] = hi;
  *(ushort4v*)&out[base + K] = lo;
}

// ------------------------------------------------- 512x512 transpose (x4 blocks)
__global__ __launch_bounds__(256)
void transpose512(const float* __restrict__ in, float* __restrict__ out)
{
  __shared__ float t[32][33];
  const size_t ao = (size_t)blockIdx.z * 512 * 512;
  const int bx = blockIdx.x * 32, by = blockIdx.y * 32;
  const int tx = threadIdx.x & 31, ty4 = (threadIdx.x >> 5) * 4;
#pragma unroll
  for (int k = 0; k < 4; ++k)
    t[ty4 + k][tx] = in[ao + (size_t)(by + ty4 + k) * 512 + bx + tx];
  __syncthreads();
#pragma unroll
  for (int k = 0; k < 4; ++k)
    out[ao + (size_t)(bx + ty4 + k) * 512 + by + tx] = t[tx][ty4 + k];
}

// ------------------------------------------------- positional bias (f64 fidelity)
__global__ __launch_bounds__(256)
void posbias_kernel(float* __restrict__ pb)
{
  const int idx = blockIdx.x * 256 + threadIdx.x;  // 2048*256
  const int j = idx >> 8;
  const int p = idx & 255;
  double ang = (double)j * exp(-(double)p * (log(10000.0) / 128.0));
  pb[(size_t)j * C_DIM + 2 * p]     = (float)sin(ang);
  pb[(size_t)j * C_DIM + 2 * p + 1] = (float)cos(ang);
}

// ------------------------------------------------- 2-pass scan: s += cumsum_b(u)
__global__ __launch_bounds__(256)
void scan_partial(const float* __restrict__ u, float* __restrict__ part)
{
  const int idx = blockIdx.x * 256 + threadIdx.x;  // 256*512
  const int g = idx >> 9, c = idx & 511;
  const float* p = u + (size_t)g * 64 * 512 + c;
  float s = 0.f;
#pragma unroll
  for (int i = 0; i < 64; ++i) s += p[i * 512];
  part[(size_t)g * 512 + c] = s;
}

// apply: block computes its own exclusive chunk-prefix (<=31 wave-uniform loads)
__global__ __launch_bounds__(256)
void scan_apply(const float* __restrict__ u, const float* __restrict__ part,
                float* __restrict__ s)
{
  const int idx = blockIdx.x * 256 + threadIdx.x;  // 256*512
  const int g = idx >> 9, c = idx & 511;
  const int a = g >> 5, ch = g & 31;
  float run = 0.f;
  for (int p = a * 32; p < a * 32 + ch; ++p)
    run += part[(size_t)p * 512 + c];
  const float* pu = u + (size_t)g * 64 * 512 + c;
  float* ps = s + (size_t)g * 64 * 512 + c;
#pragma unroll
  for (int i = 0; i < 64; ++i) {
    run += pu[i * 512];
    ps[i * 512] += run;
  }
}

// ================================================================ launcher
extern "C" void kernel_launch(void* const* d_in, const int* in_sizes, int n_in,
                              void* d_out, int out_size, void* d_ws, size_t ws_size,
                              hipStream_t stream)
{
  const float* x      = (const float*)d_in[0];
  const float* weight = (const float*)d_in[1];
  // d_in[2] = Wq, d_in[3] = Wk : dead (softmax over size-1 axis == 1.0)
  const float* Wv     = (const float*)d_in[4];
  const float* Wo     = (const float*)d_in[5];
  const float* ln1g   = (const float*)d_in[6];
  const float* ln1b   = (const float*)d_in[7];
  const float* ln2g   = (const float*)d_in[8];
  const float* ln2b   = (const float*)d_in[9];
  const float* fc1w   = (const float*)d_in[10];
  const float* fc1b   = (const float*)d_in[11];
  const float* fc2w   = (const float*)d_in[12];
  const float* fc2b   = (const float*)d_in[13];
  float* s = (float*)d_out;

  char* ws = (char*)d_ws;
  float* pb            = (float*)(ws);                                  // 4 MB
  float* u             = (float*)(ws + ((size_t)4   << 20));            // 32 MB
  float* part          = (float*)(ws + ((size_t)36  << 20));            // 0.5 MB
  unsigned short* actA = (unsigned short*)(ws + ((size_t)40  << 20));   // 32 MB
  float* wvT           = (float*)(ws + ((size_t)72  << 20));            // 4 MB
  float* wcombF        = (float*)(ws + ((size_t)76  << 20));            // 4 MB
  unsigned short* wo_s = (unsigned short*)(ws + ((size_t)80  << 20));   // 4 MB
  unsigned short* wcomb_s = (unsigned short*)(ws + ((size_t)84 << 20)); // 4 MB
  unsigned short* wvT_s   = (unsigned short*)(ws + ((size_t)90 << 20)); // 4 MB
  unsigned short* hid  = (unsigned short*)(ws + ((size_t)104 << 20));   // 128 MB
  unsigned short* w_s  = (unsigned short*)(ws + ((size_t)232 << 20));   // 2 MB
  unsigned short* fc1s = (unsigned short*)(ws + ((size_t)238 << 20));   // 4 MB
  unsigned short* fc2s = (unsigned short*)(ws + ((size_t)244 << 20));   // 4 MB

  // ---- prep (loop-invariant) ----
  posbias_kernel<<<2048, 256, 0, stream>>>(pb);
  transpose512<<<dim3(16, 16, 4), 256, 0, stream>>>(Wv, wvT);
  split2_kernel<<<dim3(1, 512),   128, 0, stream>>>(weight, w_s, 512);
  split2_kernel<<<dim3(1, 2048),  128, 0, stream>>>(fc1w, fc1s, 512);
  split2_kernel<<<dim3(4, 512),   128, 0, stream>>>(fc2w, fc2s, 2048);
  split2_kernel<<<dim3(1, 16384), 128, 0, stream>>>(x, actA, 512);
  split2_kernel<<<dim3(1, 2048),  128, 0, stream>>>(Wo, wo_s, 512);
  split2_kernel<<<dim3(1, 2048),  128, 0, stream>>>(wvT, wvT_s, 512);
  // Wcomb[a] = Wo[a] @ Wv2d[a]  (one batched launch; B base steps per 512 rows)
  gemm_bt<EPI_F32><<<dim3(4, 16, 1), 256, 0, stream>>>(
      wo_s, wvT_s, 1024, 1024, 1024, 512, 1536, 512, (long)512 * 1024,
      wcombF, nullptr, nullptr);
  split2_kernel<<<dim3(1, 2048), 128, 0, stream>>>(wcombF, wcomb_s, 512);

  // s = x @ weight^T + posbias
  gemm_bt<EPI_POSBIAS><<<dim3(4, 128, 1), 256, 0, stream>>>(
      actA, w_s, 1024, 1024, 1024, 512, 1536, 512, 0, s, pb, nullptr);

  for (int blk = 0; blk < NBLK; ++blk) {
    // h = LN1(s) -> split
    ln_split_kernel<false><<<16384, 64, 0, stream>>>(s, ln1g, ln1b, actA);
    // u = h @ Wcomb[blk]^T   (cumsum commutes with the matmul)
    gemm_bt<EPI_F32><<<dim3(4, 128, 1), 256, 0, stream>>>(
        actA, wcomb_s + (size_t)blk * 512 * 1024, 1024, 1024, 1024, 512, 1536, 512, 0,
        u, nullptr, nullptr);
    // s += cumsum_b(u)
    scan_partial<<<512, 256, 0, stream>>>(u, part);
    scan_apply<<<512, 256, 0, stream>>>(u, part, s);
    // s2 = LN2(s) + s -> split
    ln_split_kernel<true><<<16384, 64, 0, stream>>>(s, ln2g, ln2b, actA);
    // FFN over full M=16384
    gemm_bt<EPI_GELU_SPLIT><<<dim3(16, 128, 1), 256, 0, stream>>>(
        actA, fc1s, 1024, 1024, 1024, 512, 1536, 2048, 0, nullptr, fc1b, hid);
    gemm_bt<EPI_BIASCOL><<<dim3(4, 128, 1), 256, 0, stream>>>(
        hid, fc2s, 4096, 4096, 4096, 2048, 6144, 512, 0, s, fc2b, nullptr);
  }
  (void)in_sizes; (void)n_in; (void)out_size; (void)ws_size;
}